// Round 3
// baseline (1202.602 us; speedup 1.0000x reference)
//
#include <hip/hip_runtime.h>
#include <hip/hip_bf16.h>

// ---------------- problem constants ----------------
#define T_    8192
#define INDIM 1024
#define MTR   64
#define CCTX  16
#define MC    1024     // MTR*CCTX
#define NOUT  1024
#define CHUNK 64
#define NCH   128      // T_/CHUNK

using bf16x8 = __attribute__((ext_vector_type(8))) short;
using f32x4  = __attribute__((ext_vector_type(4))) float;

__device__ __forceinline__ unsigned short f2bf(float f) {
  unsigned int u = __builtin_bit_cast(unsigned int, f);
  u += 0x7fffu + ((u >> 16) & 1u);
  return (unsigned short)(u >> 16);
}

typedef __attribute__((address_space(1))) void gas_void;
typedef __attribute__((address_space(3))) void las_void;

__device__ __forceinline__ void gload_lds16(const void* g, void* l) {
  __builtin_amdgcn_global_load_lds((gas_void*)g, (las_void*)l, 16, 0, 0);
}

// ---------------- elementwise / cast kernels ----------------
__global__ __launch_bounds__(256) void cast_f32_bf16(const float* __restrict__ src,
                                                     unsigned short* __restrict__ dst, long n) {
  long i = ((long)blockIdx.x * 256 + threadIdx.x) * 4;
  if (i >= n) return;
  float4 v = *(const float4*)(src + i);
  ushort4 o = { f2bf(v.x), f2bf(v.y), f2bf(v.z), f2bf(v.w) };
  *(ushort4*)(dst + i) = o;
}

__device__ __forceinline__ float2 block_sum2(float s, float ss, float* sbuf) {
#pragma unroll
  for (int off = 32; off > 0; off >>= 1) {
    s  += __shfl_down(s, off);
    ss += __shfl_down(ss, off);
  }
  if ((threadIdx.x & 63) == 0) {
    sbuf[(threadIdx.x >> 6) * 2]     = s;
    sbuf[(threadIdx.x >> 6) * 2 + 1] = ss;
  }
  __syncthreads();
  return make_float2(sbuf[0] + sbuf[2] + sbuf[4] + sbuf[6],
                     sbuf[1] + sbuf[3] + sbuf[5] + sbuf[7]);
}

// LayerNorm(x) rows of 1024 f32 -> f32 (exact path for pre-GEMM)
__global__ __launch_bounds__(256) void ln_rows_f32(const float* __restrict__ x,
                                                   float* __restrict__ out) {
  __shared__ float sbuf[8];
  const long row = blockIdx.x;
  float4 v = ((const float4*)(x + (row << 10)))[threadIdx.x];
  float2 t = block_sum2(v.x + v.y + v.z + v.w,
                        v.x * v.x + v.y * v.y + v.z * v.z + v.w * v.w, sbuf);
  float mean = t.x * (1.f / 1024.f);
  float var  = t.y * (1.f / 1024.f) - mean * mean;
  float rstd = rsqrtf(var + 1e-5f);
  float4 o = { (v.x - mean) * rstd, (v.y - mean) * rstd,
               (v.z - mean) * rstd, (v.w - mean) * rstd };
  ((float4*)(out + (row << 10)))[threadIdx.x] = o;
}

// out = LN(p + q) rows of 1024, f32 out
__global__ __launch_bounds__(256) void ln_out_k(const float* __restrict__ p, const float* __restrict__ q,
                                                float* __restrict__ out) {
  __shared__ float sbuf[8];
  const long row = blockIdx.x;
  float4 v = ((const float4*)(p + (row << 10)))[threadIdx.x];
  float4 u = ((const float4*)(q + (row << 10)))[threadIdx.x];
  v.x += u.x; v.y += u.y; v.z += u.z; v.w += u.w;
  float2 t = block_sum2(v.x + v.y + v.z + v.w,
                        v.x * v.x + v.y * v.y + v.z * v.z + v.w * v.w, sbuf);
  float mean = t.x * (1.f / 1024.f);
  float var  = t.y * (1.f / 1024.f) - mean * mean;
  float rstd = rsqrtf(var + 1e-5f);
  float4 o = { (v.x - mean) * rstd, (v.y - mean) * rstd,
               (v.z - mean) * rstd, (v.w - mean) * rstd };
  ((float4*)(out + (row << 10)))[threadIdx.x] = o;
}

// ---------------- exact f32 pre-projection: pre[t,m] = softplus(xln[t]·pre_w[m] + pre_b[m]) ----------------
__global__ __launch_bounds__(256) void pre_gemm_k(const float* __restrict__ xln,
                                                  const float* __restrict__ pw,
                                                  const float* __restrict__ pb,
                                                  float* __restrict__ pre) {
  const int t0 = blockIdx.x * 16;
  const int m = threadIdx.x & 63;
  const int tq = threadIdx.x >> 6;
  const float4* wrow = (const float4*)(pw + (long)m * 1024);
  const float bias = pb[m];
  for (int tt = tq; tt < 16; tt += 4) {
    const float4* xrow = (const float4*)(xln + (long)(t0 + tt) * 1024);
    float a0 = 0.f, a1 = 0.f, a2 = 0.f, a3 = 0.f;
#pragma unroll 4
    for (int k = 0; k < 256; k += 4) {
      float4 w0 = wrow[k],     x0 = xrow[k];
      float4 w1 = wrow[k + 1], x1 = xrow[k + 1];
      float4 w2 = wrow[k + 2], x2 = xrow[k + 2];
      float4 w3 = wrow[k + 3], x3 = xrow[k + 3];
      a0 += w0.x * x0.x + w0.y * x0.y + w0.z * x0.z + w0.w * x0.w;
      a1 += w1.x * x1.x + w1.y * x1.y + w1.z * x1.z + w1.w * x1.w;
      a2 += w2.x * x2.x + w2.y * x2.y + w2.z * x2.z + w2.w * x2.w;
      a3 += w3.x * x3.x + w3.y * x3.y + w3.z * x3.z + w3.w * x3.w;
    }
    float v = (a0 + a1) + (a2 + a3) + bias;
    float sp = fmaxf(v, 0.f) + log1pf(expf(-fabsf(v)));
    pre[(long)(t0 + tt) * 64 + m] = sp;
  }
}

// ---------------- chunked complex reset-scan (f64 internal) for sz/out0 path ----------------
__global__ __launch_bounds__(256) void scan_p1(const float* __restrict__ pre, const int* __restrict__ start,
                                               const float* __restrict__ a, const float* __restrict__ bfr,
                                               double2* __restrict__ chA, double2* __restrict__ chB) {
  int ch = blockIdx.y * 256 + threadIdx.x;
  int m = ch >> 4, c = ch & 15;
  double dec = exp(-fabs((double)a[m]));
  double th = (double)bfr[c];
  double gre = dec * cos(th), gim = dec * sin(th);
  int j = blockIdx.x;
  int t0 = j * CHUNK;
  double pr = 1.0, pi = 0.0, sr = 0.0, si = 0.0;
  for (int t = t0; t < t0 + CHUNK; ++t) {
    double b = (double)pre[(long)t * 64 + m];
    if (start[t]) {
      pr = 0.0; pi = 0.0; sr = b; si = 0.0;
    } else {
      double nsr = gre * sr - gim * si + b;
      si = gre * si + gim * sr; sr = nsr;
      double npr = gre * pr - gim * pi;
      pi = gre * pi + gim * pr; pr = npr;
    }
  }
  chA[j * MC + ch] = make_double2(pr, pi);
  chB[j * MC + ch] = make_double2(sr, si);
}

__global__ __launch_bounds__(256) void scan_p2(const double2* __restrict__ chA, const double2* __restrict__ chB,
                                               const float* __restrict__ state0,
                                               double2* __restrict__ carry, double* __restrict__ red) {
  if (blockIdx.x == 0 && threadIdx.x < 4) red[threadIdx.x] = 0.0;
  int ch = blockIdx.x * 256 + threadIdx.x;
  double cr = (double)state0[ch], ci = 0.0;
  for (int j = 0; j < NCH; ++j) {
    carry[j * MC + ch] = make_double2(cr, ci);
    double2 A = chA[j * MC + ch];
    double2 B = chB[j * MC + ch];
    double ncr = A.x * cr - A.y * ci + B.x;
    ci = A.x * ci + A.y * cr + B.y;
    cr = ncr;
  }
}

__global__ __launch_bounds__(256) void scan_p3(const float* __restrict__ pre, const int* __restrict__ start,
                                               const float* __restrict__ a, const float* __restrict__ bfr,
                                               const double2* __restrict__ carry, float* __restrict__ sz,
                                               double* __restrict__ red) {
  __shared__ double sbuf[12];
  int ch = blockIdx.y * 256 + threadIdx.x;
  int m = ch >> 4, c = ch & 15;
  double dec = exp(-fabs((double)a[m]));
  double th = (double)bfr[c];
  double gre = dec * cos(th), gim = dec * sin(th);
  int j = blockIdx.x;
  int t0 = j * CHUNK;
  double2 cin = carry[j * MC + ch];
  double sr = cin.x, si = cin.y;
  double aR = 0.0, aI = 0.0, aS = 0.0;
  for (int t = t0; t < t0 + CHUNK; ++t) {
    double b = (double)pre[(long)t * 64 + m];
    if (start[t]) { sr = b; si = 0.0; }
    else {
      double nsr = gre * sr - gim * si + b;
      si = gre * si + gim * sr; sr = nsr;
    }
    sz[(long)t * 2048 + ch]        = (float)sr;
    sz[(long)t * 2048 + 1024 + ch] = (float)si;
    aR += sr; aI += si; aS += sr * sr + si * si;
  }
#pragma unroll
  for (int off = 32; off > 0; off >>= 1) {
    aR += __shfl_down(aR, off); aI += __shfl_down(aI, off); aS += __shfl_down(aS, off);
  }
  if ((threadIdx.x & 63) == 0) {
    int w = threadIdx.x >> 6;
    sbuf[w * 3] = aR; sbuf[w * 3 + 1] = aI; sbuf[w * 3 + 2] = aS;
  }
  __syncthreads();
  if (threadIdx.x == 0) {
    atomicAdd(&red[0], sbuf[0] + sbuf[3] + sbuf[6] + sbuf[9]);
    atomicAdd(&red[1], sbuf[1] + sbuf[4] + sbuf[7] + sbuf[10]);
    atomicAdd(&red[2], sbuf[2] + sbuf[5] + sbuf[8] + sbuf[11]);
  }
}

// ---------------- INDEPENDENT direct sequential scan for the final-state tail ----------------
// 1024 threads, each walks all T steps in f64. fmt: 2048 -> interleaved complex floats,
// 1024 -> real part only. Tail always begins at d_out + T*NOUT.
__global__ __launch_bounds__(256) void tail_direct(const float* __restrict__ pre, const int* __restrict__ start,
                                                   const float* __restrict__ a, const float* __restrict__ bfr,
                                                   const float* __restrict__ state0,
                                                   float* __restrict__ out_tail, int fmt) {
  int ch = blockIdx.x * 256 + threadIdx.x;
  int m = ch >> 4, c = ch & 15;
  double dec = exp(-fabs((double)a[m]));
  double th = (double)bfr[c];
  double gre = dec * cos(th), gim = dec * sin(th);
  double sr = (double)state0[ch], si = 0.0;
  for (int t = 0; t < T_; ++t) {
    double b = (double)pre[(long)t * 64 + m];
    if (start[t]) { sr = b; si = 0.0; }
    else {
      double nsr = gre * sr - gim * si + b;
      si = gre * si + gim * sr; sr = nsr;
    }
  }
  if (fmt == 1024) {
    out_tail[ch] = (float)sr;
  } else {
    out_tail[2 * ch]     = (float)sr;
    out_tail[2 * ch + 1] = (float)si;
  }
}

__global__ void finalize_red(const double* __restrict__ red, float* __restrict__ redf) {
  const double n = (double)T_ * (double)MC;
  double mre = red[0] / n, mim = red[1] / n;
  double var = red[2] / n - mre * mre - mim * mim;
  double sd = sqrt(var > 0.0 ? var : 0.0);
  redf[0] = (float)mre;
  redf[1] = (float)mim;
  redf[2] = (float)(1.0 / (1e-6 + sd));
}

// z[t, 0:1024]=(re-mre)*inv, z[t,1024:2048]=(im-mim)*inv -> bf16
__global__ __launch_bounds__(256) void zbuild_k(const float* __restrict__ sz, const float* __restrict__ redf,
                                                unsigned short* __restrict__ z) {
  long i = ((long)blockIdx.x * 256 + threadIdx.x) * 4;
  float mre = redf[0], mim = redf[1], inv = redf[2];
  int col = (int)(i & 2047);
  float mu = (col < 1024) ? mre : mim;
  float4 v = *(const float4*)(sz + i);
  ushort4 o = { f2bf((v.x - mu) * inv), f2bf((v.y - mu) * inv),
                f2bf((v.z - mu) * inv), f2bf((v.w - mu) * inv) };
  *(ushort4*)(z + i) = o;
}

// ---------------- bf16 MFMA GEMM (m97 structure): C[t,o] = sum_k A[t,k]*B[o,k] + bias[o] ----------------
template<int EP>
__global__ __launch_bounds__(256) void gemm_bt(const unsigned short* __restrict__ A,
                                               const unsigned short* __restrict__ B,
                                               const float* __restrict__ bias, void* __restrict__ Cout,
                                               int M_, int N_, int K_) {
  __shared__ __align__(16) unsigned short lA[128 * 32];
  __shared__ __align__(16) unsigned short lB[128 * 32];
  const int tid = threadIdx.x;
  const int lane = tid & 63;
  const int wv = tid >> 6;
  const int wr = wv >> 1, wc = wv & 1;
  const long brow = (long)blockIdx.x * 128;
  const long bcol = (long)blockIdx.y * 128;

  f32x4 acc[4][4];
#pragma unroll
  for (int i = 0; i < 4; i++)
#pragma unroll
    for (int j = 0; j < 4; j++)
      acc[i][j] = f32x4{0.f, 0.f, 0.f, 0.f};

  const int c0 = tid, c1 = tid + 256;
  const long ar0 = brow + (c0 >> 2), ar1 = brow + (c1 >> 2);
  const long br0 = bcol + (c0 >> 2), br1 = bcol + (c1 >> 2);
  const int ko0 = (c0 & 3) * 8, ko1 = (c1 & 3) * 8;
  const int r15 = lane & 15;
  const int kq = (lane >> 4) * 8;

  for (int kt = 0; kt < K_; kt += 32) {
    __syncthreads();
    gload_lds16(A + ar0 * K_ + kt + ko0, &lA[c0 * 8]);
    gload_lds16(A + ar1 * K_ + kt + ko1, &lA[c1 * 8]);
    gload_lds16(B + br0 * K_ + kt + ko0, &lB[c0 * 8]);
    gload_lds16(B + br1 * K_ + kt + ko1, &lB[c1 * 8]);
    asm volatile("s_waitcnt vmcnt(0)" ::: "memory");
    __syncthreads();
    bf16x8 af[4], bv[4];
#pragma unroll
    for (int mi = 0; mi < 4; mi++)
      af[mi] = *(const bf16x8*)&lA[(wr * 64 + mi * 16 + r15) * 32 + kq];
#pragma unroll
    for (int nj = 0; nj < 4; nj++)
      bv[nj] = *(const bf16x8*)&lB[(wc * 64 + nj * 16 + r15) * 32 + kq];
#pragma unroll
    for (int mi = 0; mi < 4; mi++)
#pragma unroll
      for (int nj = 0; nj < 4; nj++)
        acc[mi][nj] = __builtin_amdgcn_mfma_f32_16x16x32_bf16(af[mi], bv[nj], acc[mi][nj], 0, 0, 0);
  }

  const int rq = (lane >> 4) * 4;
#pragma unroll
  for (int nj = 0; nj < 4; nj++) {
    const long col = bcol + wc * 64 + nj * 16 + r15;
    const float bs = bias[col];
#pragma unroll
    for (int mi = 0; mi < 4; mi++) {
#pragma unroll
      for (int r = 0; r < 4; r++) {
        const long row = brow + wr * 64 + mi * 16 + rq + r;
        float v = acc[mi][nj][r] + bs;
        if (EP == 0) {
          ((float*)Cout)[row * N_ + col] = v;
        } else {
          float sp = (v > 20.f) ? v : log1pf(expf(v));
          float mh = v * tanhf(sp);
          ((unsigned short*)Cout)[row * N_ + col] = f2bf(mh);
        }
      }
    }
  }
}

// ---------------- host-side orchestration ----------------
extern "C" void kernel_launch(void* const* d_in, const int* in_sizes, int n_in,
                              void* d_out, int out_size, void* d_ws, size_t ws_size,
                              hipStream_t stream) {
  (void)in_sizes; (void)n_in; (void)ws_size;
  const float* x      = (const float*)d_in[0];
  const float* state0 = (const float*)d_in[1];
  const int*   start  = (const int*)d_in[2];
  const float* a      = (const float*)d_in[4];
  const float* bfr    = (const float*)d_in[5];
  const float* pre_w  = (const float*)d_in[6];
  const float* pre_b  = (const float*)d_in[7];
  const float* skip_w = (const float*)d_in[8];
  const float* skip_b = (const float*)d_in[9];
  const float* w1     = (const float*)d_in[10];
  const float* b1     = (const float*)d_in[11];
  const float* w2     = (const float*)d_in[12];
  const float* b2     = (const float*)d_in[13];
  const float* w3     = (const float*)d_in[14];
  const float* b3     = (const float*)d_in[15];

  char* ws = (char*)d_ws;
  const size_t MB = 1u << 20;
  float*          xlnf  = (float*)(ws + 0);
  float*          sz    = (float*)(ws + 0);
  float*          skipf = (float*)(ws + 0);
  float*          h3    = (float*)(ws + 32 * MB);
  unsigned short* z     = (unsigned short*)(ws + 64 * MB);
  unsigned short* xb    = (unsigned short*)(ws + 96 * MB);
  unsigned short* h2    = (unsigned short*)(ws + 96 * MB);
  unsigned short* h1    = (unsigned short*)(ws + 112 * MB);
  unsigned short* wb1   = (unsigned short*)(ws + 128 * MB);
  unsigned short* wb2   = (unsigned short*)(ws + 132 * MB);
  unsigned short* wb3   = (unsigned short*)(ws + 134 * MB);
  unsigned short* skwb  = (unsigned short*)(ws + 136 * MB);
  float*          pre   = (float*)(ws + 138 * MB);
  double2*        chA   = (double2*)(ws + 140 * MB);
  double2*        chB   = (double2*)(ws + 142 * MB);
  double2*        carry = (double2*)(ws + 144 * MB);
  double*         red   = (double*)(ws + 146 * MB);
  float*          redf  = (float*)(ws + 146 * MB + 64);

  // 1) bf16 casts for the big GEMMs
  cast_f32_bf16<<<8192, 256, 0, stream>>>(x, xb, 8388608);
  cast_f32_bf16<<<2048, 256, 0, stream>>>(w1, wb1, 2097152);
  cast_f32_bf16<<<1024, 256, 0, stream>>>(w2, wb2, 1048576);
  cast_f32_bf16<<<1024, 256, 0, stream>>>(w3, wb3, 1048576);
  cast_f32_bf16<<<1024, 256, 0, stream>>>(skip_w, skwb, 1048576);

  // 2) exact f32 path: pre = softplus(LN(x) @ pre_w^T + pre_b)
  ln_rows_f32<<<8192, 256, 0, stream>>>(x, xlnf);
  pre_gemm_k<<<512, 256, 0, stream>>>(xlnf, pre_w, pre_b, pre);

  // 3) chunked scan feeds sz / normalization; independent direct scan writes the tail
  scan_p1<<<dim3(NCH, 4), 256, 0, stream>>>(pre, start, a, bfr, chA, chB);
  scan_p2<<<4, 256, 0, stream>>>(chA, chB, state0, carry, red);
  scan_p3<<<dim3(NCH, 4), 256, 0, stream>>>(pre, start, a, bfr, carry, sz, red);
  finalize_red<<<1, 1, 0, stream>>>(red, redf);

  // tail begins right after the [T,1024] main output; format decided by out_size
  int tail_elems = out_size - T_ * NOUT;          // 2048 (interleaved complex) or 1024 (real)
  float* out_tail = (float*)d_out + (long)T_ * NOUT;
  tail_direct<<<4, 256, 0, stream>>>(pre, start, a, bfr, state0, out_tail, tail_elems);

  // 4) z = concat(scaled.re, scaled.im) in bf16
  zbuild_k<<<16384, 256, 0, stream>>>(sz, redf, z);

  // 5) skip GEMM, then the 3-layer mish MLP
  gemm_bt<0><<<dim3(64, 8), 256, 0, stream>>>(xb, skwb, skip_b, skipf, T_, 1024, 1024);
  gemm_bt<2><<<dim3(64, 8), 256, 0, stream>>>(z,  wb1, b1, h1, T_, 1024, 2048);
  gemm_bt<2><<<dim3(64, 8), 256, 0, stream>>>(h1, wb2, b2, h2, T_, 1024, 1024);
  gemm_bt<0><<<dim3(64, 8), 256, 0, stream>>>(h2, wb3, b3, h3, T_, 1024, 1024);

  // 6) out = LN(h3 + skip)
  ln_out_k<<<8192, 256, 0, stream>>>(h3, skipf, (float*)d_out);
}

// Round 4
// 648.649 us; speedup vs baseline: 1.8540x; 1.8540x over previous
//
#include <hip/hip_runtime.h>
#include <hip/hip_bf16.h>

// ---------------- problem constants ----------------
#define T_    8192
#define INDIM 1024
#define MTR   64
#define CCTX  16
#define MC    1024     // MTR*CCTX
#define NOUT  1024
#define CHUNK 64
#define NCH   128      // T_/CHUNK

using bf16x8 = __attribute__((ext_vector_type(8))) short;
using f32x4  = __attribute__((ext_vector_type(4))) float;

__device__ __forceinline__ unsigned short f2bf(float f) {
  unsigned int u = __builtin_bit_cast(unsigned int, f);
  u += 0x7fffu + ((u >> 16) & 1u);
  return (unsigned short)(u >> 16);
}

typedef __attribute__((address_space(1))) void gas_void;
typedef __attribute__((address_space(3))) void las_void;

__device__ __forceinline__ void gload_lds16(const void* g, void* l) {
  __builtin_amdgcn_global_load_lds((gas_void*)g, (las_void*)l, 16, 0, 0);
}

// ---------------- elementwise / cast kernels ----------------
__global__ __launch_bounds__(256) void cast_f32_bf16(const float* __restrict__ src,
                                                     unsigned short* __restrict__ dst, long n) {
  long i = ((long)blockIdx.x * 256 + threadIdx.x) * 4;
  if (i >= n) return;
  float4 v = *(const float4*)(src + i);
  ushort4 o = { f2bf(v.x), f2bf(v.y), f2bf(v.z), f2bf(v.w) };
  *(ushort4*)(dst + i) = o;
}

__device__ __forceinline__ float2 block_sum2(float s, float ss, float* sbuf) {
#pragma unroll
  for (int off = 32; off > 0; off >>= 1) {
    s  += __shfl_down(s, off);
    ss += __shfl_down(ss, off);
  }
  if ((threadIdx.x & 63) == 0) {
    sbuf[(threadIdx.x >> 6) * 2]     = s;
    sbuf[(threadIdx.x >> 6) * 2 + 1] = ss;
  }
  __syncthreads();
  return make_float2(sbuf[0] + sbuf[2] + sbuf[4] + sbuf[6],
                     sbuf[1] + sbuf[3] + sbuf[5] + sbuf[7]);
}

// LayerNorm(x) rows of 1024 f32 -> f32 xln (exact pre path) + bf16 cast of raw x (skip GEMM input)
__global__ __launch_bounds__(256) void ln_cast_k(const float* __restrict__ x,
                                                 float* __restrict__ xln,
                                                 unsigned short* __restrict__ xb) {
  __shared__ float sbuf[8];
  const long row = blockIdx.x;
  float4 v = ((const float4*)(x + (row << 10)))[threadIdx.x];
  // bf16 cast of raw x
  ushort4 c = { f2bf(v.x), f2bf(v.y), f2bf(v.z), f2bf(v.w) };
  ((ushort4*)(xb + (row << 10)))[threadIdx.x] = c;
  float2 t = block_sum2(v.x + v.y + v.z + v.w,
                        v.x * v.x + v.y * v.y + v.z * v.z + v.w * v.w, sbuf);
  float mean = t.x * (1.f / 1024.f);
  float var  = t.y * (1.f / 1024.f) - mean * mean;
  float rstd = rsqrtf(var + 1e-5f);
  float4 o = { (v.x - mean) * rstd, (v.y - mean) * rstd,
               (v.z - mean) * rstd, (v.w - mean) * rstd };
  ((float4*)(xln + (row << 10)))[threadIdx.x] = o;
}

// out = LN(p + q) rows of 1024, f32 out
__global__ __launch_bounds__(256) void ln_out_k(const float* __restrict__ p, const float* __restrict__ q,
                                                float* __restrict__ out) {
  __shared__ float sbuf[8];
  const long row = blockIdx.x;
  float4 v = ((const float4*)(p + (row << 10)))[threadIdx.x];
  float4 u = ((const float4*)(q + (row << 10)))[threadIdx.x];
  v.x += u.x; v.y += u.y; v.z += u.z; v.w += u.w;
  float2 t = block_sum2(v.x + v.y + v.z + v.w,
                        v.x * v.x + v.y * v.y + v.z * v.z + v.w * v.w, sbuf);
  float mean = t.x * (1.f / 1024.f);
  float var  = t.y * (1.f / 1024.f) - mean * mean;
  float rstd = rsqrtf(var + 1e-5f);
  float4 o = { (v.x - mean) * rstd, (v.y - mean) * rstd,
               (v.z - mean) * rstd, (v.w - mean) * rstd };
  ((float4*)(out + (row << 10)))[threadIdx.x] = o;
}

// ---------------- exact f32 pre-projection: pre[t,m] = softplus(xln[t]·pre_w[m] + pre_b[m]) ----------------
__global__ __launch_bounds__(256) void pre_gemm_k(const float* __restrict__ xln,
                                                  const float* __restrict__ pw,
                                                  const float* __restrict__ pb,
                                                  float* __restrict__ pre) {
  const int t0 = blockIdx.x * 16;
  const int m = threadIdx.x & 63;
  const int tq = threadIdx.x >> 6;
  const float4* wrow = (const float4*)(pw + (long)m * 1024);
  const float bias = pb[m];
  for (int tt = tq; tt < 16; tt += 4) {
    const float4* xrow = (const float4*)(xln + (long)(t0 + tt) * 1024);
    float a0 = 0.f, a1 = 0.f, a2 = 0.f, a3 = 0.f;
#pragma unroll 4
    for (int k = 0; k < 256; k += 4) {
      float4 w0 = wrow[k],     x0 = xrow[k];
      float4 w1 = wrow[k + 1], x1 = xrow[k + 1];
      float4 w2 = wrow[k + 2], x2 = xrow[k + 2];
      float4 w3 = wrow[k + 3], x3 = xrow[k + 3];
      a0 += w0.x * x0.x + w0.y * x0.y + w0.z * x0.z + w0.w * x0.w;
      a1 += w1.x * x1.x + w1.y * x1.y + w1.z * x1.z + w1.w * x1.w;
      a2 += w2.x * x2.x + w2.y * x2.y + w2.z * x2.z + w2.w * x2.w;
      a3 += w3.x * x3.x + w3.y * x3.y + w3.z * x3.z + w3.w * x3.w;
    }
    float v = (a0 + a1) + (a2 + a3) + bias;
    float sp = fmaxf(v, 0.f) + log1pf(expf(-fabsf(v)));
    pre[(long)(t0 + tt) * 64 + m] = sp;
  }
}

// ---------------- chunked complex reset-scan (f64 internal) ----------------
__global__ __launch_bounds__(256) void scan_p1(const float* __restrict__ pre, const int* __restrict__ start,
                                               const float* __restrict__ a, const float* __restrict__ bfr,
                                               double2* __restrict__ chA, double2* __restrict__ chB) {
  int ch = blockIdx.y * 256 + threadIdx.x;
  int m = ch >> 4, c = ch & 15;
  double dec = exp(-fabs((double)a[m]));
  double th = (double)bfr[c];
  double gre = dec * cos(th), gim = dec * sin(th);
  int j = blockIdx.x;
  int t0 = j * CHUNK;
  double pr = 1.0, pi = 0.0, sr = 0.0, si = 0.0;
  for (int t = t0; t < t0 + CHUNK; ++t) {
    double b = (double)pre[(long)t * 64 + m];
    if (start[t]) {
      pr = 0.0; pi = 0.0; sr = b; si = 0.0;
    } else {
      double nsr = gre * sr - gim * si + b;
      si = gre * si + gim * sr; sr = nsr;
      double npr = gre * pr - gim * pi;
      pi = gre * pi + gim * pr; pr = npr;
    }
  }
  chA[j * MC + ch] = make_double2(pr, pi);
  chB[j * MC + ch] = make_double2(sr, si);
}

// composes chunks: writes per-chunk carry, zeroes red, AND writes the final-state tail.
// fmt: 1024 -> real part only; 2048 -> interleaved complex floats.
__global__ __launch_bounds__(256) void scan_p2(const double2* __restrict__ chA, const double2* __restrict__ chB,
                                               const float* __restrict__ state0,
                                               double2* __restrict__ carry, double* __restrict__ red,
                                               float* __restrict__ out_tail, int fmt) {
  if (blockIdx.x == 0 && threadIdx.x < 4) red[threadIdx.x] = 0.0;
  int ch = blockIdx.x * 256 + threadIdx.x;
  double cr = (double)state0[ch], ci = 0.0;
  for (int j = 0; j < NCH; ++j) {
    carry[j * MC + ch] = make_double2(cr, ci);
    double2 A = chA[j * MC + ch];
    double2 B = chB[j * MC + ch];
    double ncr = A.x * cr - A.y * ci + B.x;
    ci = A.x * ci + A.y * cr + B.y;
    cr = ncr;
  }
  if (fmt == 1024) {
    out_tail[ch] = (float)cr;
  } else {
    out_tail[2 * ch]     = (float)cr;
    out_tail[2 * ch + 1] = (float)ci;
  }
}

__global__ __launch_bounds__(256) void scan_p3(const float* __restrict__ pre, const int* __restrict__ start,
                                               const float* __restrict__ a, const float* __restrict__ bfr,
                                               const double2* __restrict__ carry, float* __restrict__ sz,
                                               double* __restrict__ red) {
  __shared__ double sbuf[12];
  int ch = blockIdx.y * 256 + threadIdx.x;
  int m = ch >> 4, c = ch & 15;
  double dec = exp(-fabs((double)a[m]));
  double th = (double)bfr[c];
  double gre = dec * cos(th), gim = dec * sin(th);
  int j = blockIdx.x;
  int t0 = j * CHUNK;
  double2 cin = carry[j * MC + ch];
  double sr = cin.x, si = cin.y;
  double aR = 0.0, aI = 0.0, aS = 0.0;
  for (int t = t0; t < t0 + CHUNK; ++t) {
    double b = (double)pre[(long)t * 64 + m];
    if (start[t]) { sr = b; si = 0.0; }
    else {
      double nsr = gre * sr - gim * si + b;
      si = gre * si + gim * sr; sr = nsr;
    }
    sz[(long)t * 2048 + ch]        = (float)sr;
    sz[(long)t * 2048 + 1024 + ch] = (float)si;
    aR += sr; aI += si; aS += sr * sr + si * si;
  }
#pragma unroll
  for (int off = 32; off > 0; off >>= 1) {
    aR += __shfl_down(aR, off); aI += __shfl_down(aI, off); aS += __shfl_down(aS, off);
  }
  if ((threadIdx.x & 63) == 0) {
    int w = threadIdx.x >> 6;
    sbuf[w * 3] = aR; sbuf[w * 3 + 1] = aI; sbuf[w * 3 + 2] = aS;
  }
  __syncthreads();
  if (threadIdx.x == 0) {
    atomicAdd(&red[0], sbuf[0] + sbuf[3] + sbuf[6] + sbuf[9]);
    atomicAdd(&red[1], sbuf[1] + sbuf[4] + sbuf[7] + sbuf[10]);
    atomicAdd(&red[2], sbuf[2] + sbuf[5] + sbuf[8] + sbuf[11]);
  }
}

__global__ void finalize_red(const double* __restrict__ red, float* __restrict__ redf) {
  const double n = (double)T_ * (double)MC;
  double mre = red[0] / n, mim = red[1] / n;
  double var = red[2] / n - mre * mre - mim * mim;
  double sd = sqrt(var > 0.0 ? var : 0.0);
  redf[0] = (float)mre;
  redf[1] = (float)mim;
  redf[2] = (float)(1.0 / (1e-6 + sd));
}

// z[t, 0:1024]=(re-mre)*inv, z[t,1024:2048]=(im-mim)*inv -> bf16
__global__ __launch_bounds__(256) void zbuild_k(const float* __restrict__ sz, const float* __restrict__ redf,
                                                unsigned short* __restrict__ z) {
  long i = ((long)blockIdx.x * 256 + threadIdx.x) * 4;
  float mre = redf[0], mim = redf[1], inv = redf[2];
  int col = (int)(i & 2047);
  float mu = (col < 1024) ? mre : mim;
  float4 v = *(const float4*)(sz + i);
  ushort4 o = { f2bf((v.x - mu) * inv), f2bf((v.y - mu) * inv),
                f2bf((v.z - mu) * inv), f2bf((v.w - mu) * inv) };
  *(ushort4*)(z + i) = o;
}

// ---------------- bf16 MFMA GEMM (m97 structure): C[t,o] = sum_k A[t,k]*B[o,k] + bias[o] ----------------
template<int EP>
__global__ __launch_bounds__(256) void gemm_bt(const unsigned short* __restrict__ A,
                                               const unsigned short* __restrict__ B,
                                               const float* __restrict__ bias, void* __restrict__ Cout,
                                               int M_, int N_, int K_) {
  __shared__ __align__(16) unsigned short lA[128 * 32];
  __shared__ __align__(16) unsigned short lB[128 * 32];
  const int tid = threadIdx.x;
  const int lane = tid & 63;
  const int wv = tid >> 6;
  const int wr = wv >> 1, wc = wv & 1;
  const long brow = (long)blockIdx.x * 128;
  const long bcol = (long)blockIdx.y * 128;

  f32x4 acc[4][4];
#pragma unroll
  for (int i = 0; i < 4; i++)
#pragma unroll
    for (int j = 0; j < 4; j++)
      acc[i][j] = f32x4{0.f, 0.f, 0.f, 0.f};

  const int c0 = tid, c1 = tid + 256;
  const long ar0 = brow + (c0 >> 2), ar1 = brow + (c1 >> 2);
  const long br0 = bcol + (c0 >> 2), br1 = bcol + (c1 >> 2);
  const int ko0 = (c0 & 3) * 8, ko1 = (c1 & 3) * 8;
  const int r15 = lane & 15;
  const int kq = (lane >> 4) * 8;

  for (int kt = 0; kt < K_; kt += 32) {
    __syncthreads();
    gload_lds16(A + ar0 * K_ + kt + ko0, &lA[c0 * 8]);
    gload_lds16(A + ar1 * K_ + kt + ko1, &lA[c1 * 8]);
    gload_lds16(B + br0 * K_ + kt + ko0, &lB[c0 * 8]);
    gload_lds16(B + br1 * K_ + kt + ko1, &lB[c1 * 8]);
    asm volatile("s_waitcnt vmcnt(0)" ::: "memory");
    __syncthreads();
    bf16x8 af[4], bv[4];
#pragma unroll
    for (int mi = 0; mi < 4; mi++)
      af[mi] = *(const bf16x8*)&lA[(wr * 64 + mi * 16 + r15) * 32 + kq];
#pragma unroll
    for (int nj = 0; nj < 4; nj++)
      bv[nj] = *(const bf16x8*)&lB[(wc * 64 + nj * 16 + r15) * 32 + kq];
#pragma unroll
    for (int mi = 0; mi < 4; mi++)
#pragma unroll
      for (int nj = 0; nj < 4; nj++)
        acc[mi][nj] = __builtin_amdgcn_mfma_f32_16x16x32_bf16(af[mi], bv[nj], acc[mi][nj], 0, 0, 0);
  }

  const int rq = (lane >> 4) * 4;
#pragma unroll
  for (int nj = 0; nj < 4; nj++) {
    const long col = bcol + wc * 64 + nj * 16 + r15;
    const float bs = bias[col];
#pragma unroll
    for (int mi = 0; mi < 4; mi++) {
#pragma unroll
      for (int r = 0; r < 4; r++) {
        const long row = brow + wr * 64 + mi * 16 + rq + r;
        float v = acc[mi][nj][r] + bs;
        if (EP == 0) {
          ((float*)Cout)[row * N_ + col] = v;
        } else {
          float sp = (v > 20.f) ? v : log1pf(expf(v));
          float mh = v * tanhf(sp);
          ((unsigned short*)Cout)[row * N_ + col] = f2bf(mh);
        }
      }
    }
  }
}

// ---------------- host-side orchestration ----------------
extern "C" void kernel_launch(void* const* d_in, const int* in_sizes, int n_in,
                              void* d_out, int out_size, void* d_ws, size_t ws_size,
                              hipStream_t stream) {
  (void)in_sizes; (void)n_in; (void)ws_size;
  const float* x      = (const float*)d_in[0];
  const float* state0 = (const float*)d_in[1];
  const int*   start  = (const int*)d_in[2];
  const float* a      = (const float*)d_in[4];
  const float* bfr    = (const float*)d_in[5];
  const float* pre_w  = (const float*)d_in[6];
  const float* pre_b  = (const float*)d_in[7];
  const float* skip_w = (const float*)d_in[8];
  const float* skip_b = (const float*)d_in[9];
  const float* w1     = (const float*)d_in[10];
  const float* b1     = (const float*)d_in[11];
  const float* w2     = (const float*)d_in[12];
  const float* b2     = (const float*)d_in[13];
  const float* w3     = (const float*)d_in[14];
  const float* b3     = (const float*)d_in[15];

  char* ws = (char*)d_ws;
  const size_t MB = 1u << 20;
  float*          xlnf  = (float*)(ws + 0);
  float*          sz    = (float*)(ws + 0);
  float*          skipf = (float*)(ws + 0);
  float*          h3    = (float*)(ws + 32 * MB);
  unsigned short* z     = (unsigned short*)(ws + 64 * MB);
  unsigned short* xb    = (unsigned short*)(ws + 96 * MB);
  unsigned short* h2    = (unsigned short*)(ws + 96 * MB);
  unsigned short* h1    = (unsigned short*)(ws + 112 * MB);
  unsigned short* wb1   = (unsigned short*)(ws + 128 * MB);
  unsigned short* wb2   = (unsigned short*)(ws + 132 * MB);
  unsigned short* wb3   = (unsigned short*)(ws + 134 * MB);
  unsigned short* skwb  = (unsigned short*)(ws + 136 * MB);
  float*          pre   = (float*)(ws + 138 * MB);
  double2*        chA   = (double2*)(ws + 140 * MB);
  double2*        chB   = (double2*)(ws + 142 * MB);
  double2*        carry = (double2*)(ws + 144 * MB);
  double*         red   = (double*)(ws + 146 * MB);
  float*          redf  = (float*)(ws + 146 * MB + 64);

  // NOTE: xlnf aliases sz; xlnf is consumed by pre_gemm_k BEFORE scan_p3 writes sz.

  // 1) weight casts for the big GEMMs
  cast_f32_bf16<<<2048, 256, 0, stream>>>(w1, wb1, 2097152);
  cast_f32_bf16<<<1024, 256, 0, stream>>>(w2, wb2, 1048576);
  cast_f32_bf16<<<1024, 256, 0, stream>>>(w3, wb3, 1048576);
  cast_f32_bf16<<<1024, 256, 0, stream>>>(skip_w, skwb, 1048576);

  // 2) fused: xln = LN(x) (f32) + xb = bf16(x); then exact f32 pre-projection
  ln_cast_k<<<8192, 256, 0, stream>>>(x, xlnf, xb);
  pre_gemm_k<<<512, 256, 0, stream>>>(xlnf, pre_w, pre_b, pre);

  // 3) chunked scan; p2 composes carries and writes the final-state tail directly
  int tail_elems = out_size - T_ * NOUT;          // 1024 (real only) or 2048 (interleaved)
  float* out_tail = (float*)d_out + (long)T_ * NOUT;
  scan_p1<<<dim3(NCH, 4), 256, 0, stream>>>(pre, start, a, bfr, chA, chB);
  scan_p2<<<4, 256, 0, stream>>>(chA, chB, state0, carry, red, out_tail, tail_elems);
  scan_p3<<<dim3(NCH, 4), 256, 0, stream>>>(pre, start, a, bfr, carry, sz, red);
  finalize_red<<<1, 1, 0, stream>>>(red, redf);

  // 4) z = concat(scaled.re, scaled.im) in bf16
  zbuild_k<<<16384, 256, 0, stream>>>(sz, redf, z);

  // 5) skip GEMM, then the 3-layer mish MLP
  gemm_bt<0><<<dim3(64, 8), 256, 0, stream>>>(xb, skwb, skip_b, skipf, T_, 1024, 1024);
  gemm_bt<2><<<dim3(64, 8), 256, 0, stream>>>(z,  wb1, b1, h1, T_, 1024, 2048);
  gemm_bt<2><<<dim3(64, 8), 256, 0, stream>>>(h1, wb2, b2, h2, T_, 1024, 1024);
  gemm_bt<0><<<dim3(64, 8), 256, 0, stream>>>(h2, wb3, b3, h3, T_, 1024, 1024);

  // 6) out = LN(h3 + skip)
  ln_out_k<<<8192, 256, 0, stream>>>(h3, skipf, (float*)d_out);
}

// Round 5
// 422.175 us; speedup vs baseline: 2.8486x; 1.5364x over previous
//
#include <hip/hip_runtime.h>
#include <hip/hip_bf16.h>

// ---------------- problem constants ----------------
#define T_    8192
#define INDIM 1024
#define MTR   64
#define CCTX  16
#define MC    1024     // MTR*CCTX
#define NOUT  1024
#define CHUNK 64
#define NCH   128      // T_/CHUNK

using bf16x8 = __attribute__((ext_vector_type(8))) short;
using f32x4  = __attribute__((ext_vector_type(4))) float;

__device__ __forceinline__ unsigned short f2bf(float f) {
  unsigned int u = __builtin_bit_cast(unsigned int, f);
  u += 0x7fffu + ((u >> 16) & 1u);
  return (unsigned short)(u >> 16);
}

typedef __attribute__((address_space(1))) void gas_void;
typedef __attribute__((address_space(3))) void las_void;

__device__ __forceinline__ void gload_lds16(const void* g, void* l) {
  __builtin_amdgcn_global_load_lds((gas_void*)g, (las_void*)l, 16, 0, 0);
}

// ---------------- elementwise / cast kernels ----------------
__global__ __launch_bounds__(256) void cast_f32_bf16(const float* __restrict__ src,
                                                     unsigned short* __restrict__ dst, long n) {
  long i = ((long)blockIdx.x * 256 + threadIdx.x) * 4;
  if (i >= n) return;
  float4 v = *(const float4*)(src + i);
  ushort4 o = { f2bf(v.x), f2bf(v.y), f2bf(v.z), f2bf(v.w) };
  *(ushort4*)(dst + i) = o;
}

__device__ __forceinline__ float2 block_sum2(float s, float ss, float* sbuf) {
#pragma unroll
  for (int off = 32; off > 0; off >>= 1) {
    s  += __shfl_down(s, off);
    ss += __shfl_down(ss, off);
  }
  if ((threadIdx.x & 63) == 0) {
    sbuf[(threadIdx.x >> 6) * 2]     = s;
    sbuf[(threadIdx.x >> 6) * 2 + 1] = ss;
  }
  __syncthreads();
  return make_float2(sbuf[0] + sbuf[2] + sbuf[4] + sbuf[6],
                     sbuf[1] + sbuf[3] + sbuf[5] + sbuf[7]);
}

// LayerNorm(x) rows of 1024 f32 -> f32 xln (exact pre path) + bf16 cast of raw x (skip GEMM input)
__global__ __launch_bounds__(256) void ln_cast_k(const float* __restrict__ x,
                                                 float* __restrict__ xln,
                                                 unsigned short* __restrict__ xb) {
  __shared__ float sbuf[8];
  const long row = blockIdx.x;
  float4 v = ((const float4*)(x + (row << 10)))[threadIdx.x];
  ushort4 c = { f2bf(v.x), f2bf(v.y), f2bf(v.z), f2bf(v.w) };
  ((ushort4*)(xb + (row << 10)))[threadIdx.x] = c;
  float2 t = block_sum2(v.x + v.y + v.z + v.w,
                        v.x * v.x + v.y * v.y + v.z * v.z + v.w * v.w, sbuf);
  float mean = t.x * (1.f / 1024.f);
  float var  = t.y * (1.f / 1024.f) - mean * mean;
  float rstd = rsqrtf(var + 1e-5f);
  float4 o = { (v.x - mean) * rstd, (v.y - mean) * rstd,
               (v.z - mean) * rstd, (v.w - mean) * rstd };
  ((float4*)(xln + (row << 10)))[threadIdx.x] = o;
}

// out = LN(p + q) rows of 1024, f32 out
__global__ __launch_bounds__(256) void ln_out_k(const float* __restrict__ p, const float* __restrict__ q,
                                                float* __restrict__ out) {
  __shared__ float sbuf[8];
  const long row = blockIdx.x;
  float4 v = ((const float4*)(p + (row << 10)))[threadIdx.x];
  float4 u = ((const float4*)(q + (row << 10)))[threadIdx.x];
  v.x += u.x; v.y += u.y; v.z += u.z; v.w += u.w;
  float2 t = block_sum2(v.x + v.y + v.z + v.w,
                        v.x * v.x + v.y * v.y + v.z * v.z + v.w * v.w, sbuf);
  float mean = t.x * (1.f / 1024.f);
  float var  = t.y * (1.f / 1024.f) - mean * mean;
  float rstd = rsqrtf(var + 1e-5f);
  float4 o = { (v.x - mean) * rstd, (v.y - mean) * rstd,
               (v.z - mean) * rstd, (v.w - mean) * rstd };
  ((float4*)(out + (row << 10)))[threadIdx.x] = o;
}

// ---------------- exact f32 pre-projection (LDS-tiled): pre[t,m] = softplus(xln[t]·pre_w[m] + pre_b[m]) ----------------
// block = 32 t-rows, 256 threads. m = tid&63, tg = tid>>6 owns 8 t-rows.
// xln chunk [32][128] staged in LDS; reads are wave-uniform broadcasts (conflict-free).
__global__ __launch_bounds__(256) void pre_gemm_k(const float* __restrict__ xln,
                                                  const float* __restrict__ pw,
                                                  const float* __restrict__ pb,
                                                  float* __restrict__ pre) {
  __shared__ __align__(16) float xs[32][128];
  const int t0 = blockIdx.x * 32;
  const int m  = threadIdx.x & 63;
  const int tg = threadIdx.x >> 6;          // 0..3
  float acc[8];
#pragma unroll
  for (int i = 0; i < 8; i++) acc[i] = 0.f;

  for (int kc = 0; kc < 1024; kc += 128) {
    __syncthreads();
    // cooperative load: 32 rows x 128 cols = 1024 float4; 4 per thread
#pragma unroll
    for (int r = 0; r < 4; ++r) {
      int idx  = threadIdx.x + 256 * r;     // 0..1023
      int row  = idx >> 5;                  // 32 float4 per row
      int col4 = idx & 31;
      ((float4*)xs[row])[col4] = ((const float4*)(xln + (long)(t0 + row) * 1024 + kc))[col4];
    }
    __syncthreads();
    const float4* wrow4 = (const float4*)(pw + (long)m * 1024 + kc);
#pragma unroll 8
    for (int k4 = 0; k4 < 32; ++k4) {
      float4 w4 = wrow4[k4];
#pragma unroll
      for (int tt = 0; tt < 8; ++tt) {
        float4 xv = ((const float4*)xs[tg * 8 + tt])[k4];
        acc[tt] += w4.x * xv.x + w4.y * xv.y + w4.z * xv.z + w4.w * xv.w;
      }
    }
  }
  const float bias = pb[m];
#pragma unroll
  for (int tt = 0; tt < 8; ++tt) {
    float v = acc[tt] + bias;
    float sp = fmaxf(v, 0.f) + log1pf(expf(-fabsf(v)));
    pre[(long)(t0 + tg * 8 + tt) * 64 + m] = sp;
  }
}

// ---------------- chunked complex reset-scan (f64 internal) ----------------
__global__ __launch_bounds__(256) void scan_p1(const float* __restrict__ pre, const int* __restrict__ start,
                                               const float* __restrict__ a, const float* __restrict__ bfr,
                                               double2* __restrict__ chA, double2* __restrict__ chB) {
  int ch = blockIdx.y * 256 + threadIdx.x;
  int m = ch >> 4, c = ch & 15;
  double dec = exp(-fabs((double)a[m]));
  double th = (double)bfr[c];
  double gre = dec * cos(th), gim = dec * sin(th);
  int j = blockIdx.x;
  int t0 = j * CHUNK;
  double pr = 1.0, pi = 0.0, sr = 0.0, si = 0.0;
  for (int t = t0; t < t0 + CHUNK; ++t) {
    double b = (double)pre[(long)t * 64 + m];
    if (start[t]) {
      pr = 0.0; pi = 0.0; sr = b; si = 0.0;
    } else {
      double nsr = gre * sr - gim * si + b;
      si = gre * si + gim * sr; sr = nsr;
      double npr = gre * pr - gim * pi;
      pi = gre * pi + gim * pr; pr = npr;
    }
  }
  chA[j * MC + ch] = make_double2(pr, pi);
  chB[j * MC + ch] = make_double2(sr, si);
}

// composes chunks: writes per-chunk carry, zeroes red, AND writes the final-state tail.
// fmt: 1024 -> real part only; 2048 -> interleaved complex floats.
__global__ __launch_bounds__(256) void scan_p2(const double2* __restrict__ chA, const double2* __restrict__ chB,
                                               const float* __restrict__ state0,
                                               double2* __restrict__ carry, double* __restrict__ red,
                                               float* __restrict__ out_tail, int fmt) {
  if (blockIdx.x == 0 && threadIdx.x < 4) red[threadIdx.x] = 0.0;
  int ch = blockIdx.x * 256 + threadIdx.x;
  double cr = (double)state0[ch], ci = 0.0;
  for (int j = 0; j < NCH; ++j) {
    carry[j * MC + ch] = make_double2(cr, ci);
    double2 A = chA[j * MC + ch];
    double2 B = chB[j * MC + ch];
    double ncr = A.x * cr - A.y * ci + B.x;
    ci = A.x * ci + A.y * cr + B.y;
    cr = ncr;
  }
  if (fmt == 1024) {
    out_tail[ch] = (float)cr;
  } else {
    out_tail[2 * ch]     = (float)cr;
    out_tail[2 * ch + 1] = (float)ci;
  }
}

__global__ __launch_bounds__(256) void scan_p3(const float* __restrict__ pre, const int* __restrict__ start,
                                               const float* __restrict__ a, const float* __restrict__ bfr,
                                               const double2* __restrict__ carry, float* __restrict__ sz,
                                               double* __restrict__ red) {
  __shared__ double sbuf[12];
  int ch = blockIdx.y * 256 + threadIdx.x;
  int m = ch >> 4, c = ch & 15;
  double dec = exp(-fabs((double)a[m]));
  double th = (double)bfr[c];
  double gre = dec * cos(th), gim = dec * sin(th);
  int j = blockIdx.x;
  int t0 = j * CHUNK;
  double2 cin = carry[j * MC + ch];
  double sr = cin.x, si = cin.y;
  double aR = 0.0, aI = 0.0, aS = 0.0;
  for (int t = t0; t < t0 + CHUNK; ++t) {
    double b = (double)pre[(long)t * 64 + m];
    if (start[t]) { sr = b; si = 0.0; }
    else {
      double nsr = gre * sr - gim * si + b;
      si = gre * si + gim * sr; sr = nsr;
    }
    sz[(long)t * 2048 + ch]        = (float)sr;
    sz[(long)t * 2048 + 1024 + ch] = (float)si;
    aR += sr; aI += si; aS += sr * sr + si * si;
  }
#pragma unroll
  for (int off = 32; off > 0; off >>= 1) {
    aR += __shfl_down(aR, off); aI += __shfl_down(aI, off); aS += __shfl_down(aS, off);
  }
  if ((threadIdx.x & 63) == 0) {
    int w = threadIdx.x >> 6;
    sbuf[w * 3] = aR; sbuf[w * 3 + 1] = aI; sbuf[w * 3 + 2] = aS;
  }
  __syncthreads();
  if (threadIdx.x == 0) {
    atomicAdd(&red[0], sbuf[0] + sbuf[3] + sbuf[6] + sbuf[9]);
    atomicAdd(&red[1], sbuf[1] + sbuf[4] + sbuf[7] + sbuf[10]);
    atomicAdd(&red[2], sbuf[2] + sbuf[5] + sbuf[8] + sbuf[11]);
  }
}

__global__ void finalize_red(const double* __restrict__ red, float* __restrict__ redf) {
  const double n = (double)T_ * (double)MC;
  double mre = red[0] / n, mim = red[1] / n;
  double var = red[2] / n - mre * mre - mim * mim;
  double sd = sqrt(var > 0.0 ? var : 0.0);
  redf[0] = (float)mre;
  redf[1] = (float)mim;
  redf[2] = (float)(1.0 / (1e-6 + sd));
}

// z[t, 0:1024]=(re-mre)*inv, z[t,1024:2048]=(im-mim)*inv -> bf16
__global__ __launch_bounds__(256) void zbuild_k(const float* __restrict__ sz, const float* __restrict__ redf,
                                                unsigned short* __restrict__ z) {
  long i = ((long)blockIdx.x * 256 + threadIdx.x) * 4;
  float mre = redf[0], mim = redf[1], inv = redf[2];
  int col = (int)(i & 2047);
  float mu = (col < 1024) ? mre : mim;
  float4 v = *(const float4*)(sz + i);
  ushort4 o = { f2bf((v.x - mu) * inv), f2bf((v.y - mu) * inv),
                f2bf((v.z - mu) * inv), f2bf((v.w - mu) * inv) };
  *(ushort4*)(z + i) = o;
}

// ---------------- bf16 MFMA GEMM (m97 structure): C[t,o] = sum_k A[t,k]*B[o,k] + bias[o] ----------------
template<int EP>
__global__ __launch_bounds__(256) void gemm_bt(const unsigned short* __restrict__ A,
                                               const unsigned short* __restrict__ B,
                                               const float* __restrict__ bias, void* __restrict__ Cout,
                                               int M_, int N_, int K_) {
  __shared__ __align__(16) unsigned short lA[128 * 32];
  __shared__ __align__(16) unsigned short lB[128 * 32];
  const int tid = threadIdx.x;
  const int lane = tid & 63;
  const int wv = tid >> 6;
  const int wr = wv >> 1, wc = wv & 1;
  const long brow = (long)blockIdx.x * 128;
  const long bcol = (long)blockIdx.y * 128;

  f32x4 acc[4][4];
#pragma unroll
  for (int i = 0; i < 4; i++)
#pragma unroll
    for (int j = 0; j < 4; j++)
      acc[i][j] = f32x4{0.f, 0.f, 0.f, 0.f};

  const int c0 = tid, c1 = tid + 256;
  const long ar0 = brow + (c0 >> 2), ar1 = brow + (c1 >> 2);
  const long br0 = bcol + (c0 >> 2), br1 = bcol + (c1 >> 2);
  const int ko0 = (c0 & 3) * 8, ko1 = (c1 & 3) * 8;
  const int r15 = lane & 15;
  const int kq = (lane >> 4) * 8;

  for (int kt = 0; kt < K_; kt += 32) {
    __syncthreads();
    gload_lds16(A + ar0 * K_ + kt + ko0, &lA[c0 * 8]);
    gload_lds16(A + ar1 * K_ + kt + ko1, &lA[c1 * 8]);
    gload_lds16(B + br0 * K_ + kt + ko0, &lB[c0 * 8]);
    gload_lds16(B + br1 * K_ + kt + ko1, &lB[c1 * 8]);
    asm volatile("s_waitcnt vmcnt(0)" ::: "memory");
    __syncthreads();
    bf16x8 af[4], bv[4];
#pragma unroll
    for (int mi = 0; mi < 4; mi++)
      af[mi] = *(const bf16x8*)&lA[(wr * 64 + mi * 16 + r15) * 32 + kq];
#pragma unroll
    for (int nj = 0; nj < 4; nj++)
      bv[nj] = *(const bf16x8*)&lB[(wc * 64 + nj * 16 + r15) * 32 + kq];
#pragma unroll
    for (int mi = 0; mi < 4; mi++)
#pragma unroll
      for (int nj = 0; nj < 4; nj++)
        acc[mi][nj] = __builtin_amdgcn_mfma_f32_16x16x32_bf16(af[mi], bv[nj], acc[mi][nj], 0, 0, 0);
  }

  const int rq = (lane >> 4) * 4;
#pragma unroll
  for (int nj = 0; nj < 4; nj++) {
    const long col = bcol + wc * 64 + nj * 16 + r15;
    const float bs = bias[col];
#pragma unroll
    for (int mi = 0; mi < 4; mi++) {
#pragma unroll
      for (int r = 0; r < 4; r++) {
        const long row = brow + wr * 64 + mi * 16 + rq + r;
        float v = acc[mi][nj][r] + bs;
        if (EP == 0) {
          ((float*)Cout)[row * N_ + col] = v;
        } else {
          float sp = (v > 20.f) ? v : log1pf(expf(v));
          float mh = v * tanhf(sp);
          ((unsigned short*)Cout)[row * N_ + col] = f2bf(mh);
        }
      }
    }
  }
}

// ---------------- host-side orchestration ----------------
extern "C" void kernel_launch(void* const* d_in, const int* in_sizes, int n_in,
                              void* d_out, int out_size, void* d_ws, size_t ws_size,
                              hipStream_t stream) {
  (void)in_sizes; (void)n_in; (void)ws_size;
  const float* x      = (const float*)d_in[0];
  const float* state0 = (const float*)d_in[1];
  const int*   start  = (const int*)d_in[2];
  const float* a      = (const float*)d_in[4];
  const float* bfr    = (const float*)d_in[5];
  const float* pre_w  = (const float*)d_in[6];
  const float* pre_b  = (const float*)d_in[7];
  const float* skip_w = (const float*)d_in[8];
  const float* skip_b = (const float*)d_in[9];
  const float* w1     = (const float*)d_in[10];
  const float* b1     = (const float*)d_in[11];
  const float* w2     = (const float*)d_in[12];
  const float* b2     = (const float*)d_in[13];
  const float* w3     = (const float*)d_in[14];
  const float* b3     = (const float*)d_in[15];

  char* ws = (char*)d_ws;
  const size_t MB = 1u << 20;
  float*          xlnf  = (float*)(ws + 0);
  float*          sz    = (float*)(ws + 0);
  float*          skipf = (float*)(ws + 0);
  float*          h3    = (float*)(ws + 32 * MB);
  unsigned short* z     = (unsigned short*)(ws + 64 * MB);
  unsigned short* xb    = (unsigned short*)(ws + 96 * MB);
  unsigned short* h2    = (unsigned short*)(ws + 96 * MB);
  unsigned short* h1    = (unsigned short*)(ws + 112 * MB);
  unsigned short* wb1   = (unsigned short*)(ws + 128 * MB);
  unsigned short* wb2   = (unsigned short*)(ws + 132 * MB);
  unsigned short* wb3   = (unsigned short*)(ws + 134 * MB);
  unsigned short* skwb  = (unsigned short*)(ws + 136 * MB);
  float*          pre   = (float*)(ws + 138 * MB);
  double2*        chA   = (double2*)(ws + 140 * MB);
  double2*        chB   = (double2*)(ws + 142 * MB);
  double2*        carry = (double2*)(ws + 144 * MB);
  double*         red   = (double*)(ws + 146 * MB);
  float*          redf  = (float*)(ws + 146 * MB + 64);

  // NOTE: xlnf aliases sz; xlnf is consumed by pre_gemm_k BEFORE scan_p3 writes sz.

  // 1) weight casts for the big GEMMs
  cast_f32_bf16<<<2048, 256, 0, stream>>>(w1, wb1, 2097152);
  cast_f32_bf16<<<1024, 256, 0, stream>>>(w2, wb2, 1048576);
  cast_f32_bf16<<<1024, 256, 0, stream>>>(w3, wb3, 1048576);
  cast_f32_bf16<<<1024, 256, 0, stream>>>(skip_w, skwb, 1048576);

  // 2) fused: xln = LN(x) (f32) + xb = bf16(x); then exact f32 pre-projection (LDS-tiled)
  ln_cast_k<<<8192, 256, 0, stream>>>(x, xlnf, xb);
  pre_gemm_k<<<256, 256, 0, stream>>>(xlnf, pre_w, pre_b, pre);

  // 3) chunked scan; p2 composes carries and writes the final-state tail directly
  int tail_elems = out_size - T_ * NOUT;          // 1024 (real only) or 2048 (interleaved)
  float* out_tail = (float*)d_out + (long)T_ * NOUT;
  scan_p1<<<dim3(NCH, 4), 256, 0, stream>>>(pre, start, a, bfr, chA, chB);
  scan_p2<<<4, 256, 0, stream>>>(chA, chB, state0, carry, red, out_tail, tail_elems);
  scan_p3<<<dim3(NCH, 4), 256, 0, stream>>>(pre, start, a, bfr, carry, sz, red);
  finalize_red<<<1, 1, 0, stream>>>(red, redf);

  // 4) z = concat(scaled.re, scaled.im) in bf16
  zbuild_k<<<16384, 256, 0, stream>>>(sz, redf, z);

  // 5) skip GEMM, then the 3-layer mish MLP
  gemm_bt<0><<<dim3(64, 8), 256, 0, stream>>>(xb, skwb, skip_b, skipf, T_, 1024, 1024);
  gemm_bt<2><<<dim3(64, 8), 256, 0, stream>>>(z,  wb1, b1, h1, T_, 1024, 2048);
  gemm_bt<2><<<dim3(64, 8), 256, 0, stream>>>(h1, wb2, b2, h2, T_, 1024, 1024);
  gemm_bt<0><<<dim3(64, 8), 256, 0, stream>>>(h2, wb3, b3, h3, T_, 1024, 1024);

  // 6) out = LN(h3 + skip)
  ln_out_k<<<8192, 256, 0, stream>>>(h3, skipf, (float*)d_out);
}

// Round 6
// 346.935 us; speedup vs baseline: 3.4664x; 1.2169x over previous
//
#include <hip/hip_runtime.h>
#include <hip/hip_bf16.h>

// ---------------- problem constants ----------------
#define T_    8192
#define INDIM 1024
#define MTR   64
#define CCTX  16
#define MC    1024     // MTR*CCTX
#define NOUT  1024
#define CHUNK 64
#define NCH   128      // T_/CHUNK

using bf16x8 = __attribute__((ext_vector_type(8))) short;
using f32x4  = __attribute__((ext_vector_type(4))) float;

__device__ __forceinline__ unsigned short f2bf(float f) {
  unsigned int u = __builtin_bit_cast(unsigned int, f);
  u += 0x7fffu + ((u >> 16) & 1u);
  return (unsigned short)(u >> 16);
}

// cheap mish: v * tanh(softplus(v)) = v * w/(w+2), w = e^v*(e^v+2); v>20 -> v
__device__ __forceinline__ float mish_f(float v) {
  float u = __expf(v);
  float w = u * (u + 2.f);
  return (v > 20.f) ? v : v * __fdividef(w, w + 2.f);
}

typedef __attribute__((address_space(1))) void gas_void;
typedef __attribute__((address_space(3))) void las_void;

__device__ __forceinline__ void gload_lds16(const void* g, void* l) {
  __builtin_amdgcn_global_load_lds((gas_void*)g, (las_void*)l, 16, 0, 0);
}

// ---------------- elementwise / cast kernels ----------------
__global__ __launch_bounds__(256) void cast_f32_bf16(const float* __restrict__ src,
                                                     unsigned short* __restrict__ dst, long n) {
  long i = ((long)blockIdx.x * 256 + threadIdx.x) * 4;
  if (i >= n) return;
  float4 v = *(const float4*)(src + i);
  ushort4 o = { f2bf(v.x), f2bf(v.y), f2bf(v.z), f2bf(v.w) };
  *(ushort4*)(dst + i) = o;
}

__device__ __forceinline__ float2 block_sum2(float s, float ss, float* sbuf) {
#pragma unroll
  for (int off = 32; off > 0; off >>= 1) {
    s  += __shfl_down(s, off);
    ss += __shfl_down(ss, off);
  }
  if ((threadIdx.x & 63) == 0) {
    sbuf[(threadIdx.x >> 6) * 2]     = s;
    sbuf[(threadIdx.x >> 6) * 2 + 1] = ss;
  }
  __syncthreads();
  return make_float2(sbuf[0] + sbuf[2] + sbuf[4] + sbuf[6],
                     sbuf[1] + sbuf[3] + sbuf[5] + sbuf[7]);
}

// LayerNorm(x) rows of 1024 f32 -> f32 xln (exact pre path) + bf16 cast of raw x (skip GEMM input)
__global__ __launch_bounds__(256) void ln_cast_k(const float* __restrict__ x,
                                                 float* __restrict__ xln,
                                                 unsigned short* __restrict__ xb) {
  __shared__ float sbuf[8];
  const long row = blockIdx.x;
  float4 v = ((const float4*)(x + (row << 10)))[threadIdx.x];
  ushort4 c = { f2bf(v.x), f2bf(v.y), f2bf(v.z), f2bf(v.w) };
  ((ushort4*)(xb + (row << 10)))[threadIdx.x] = c;
  float2 t = block_sum2(v.x + v.y + v.z + v.w,
                        v.x * v.x + v.y * v.y + v.z * v.z + v.w * v.w, sbuf);
  float mean = t.x * (1.f / 1024.f);
  float var  = t.y * (1.f / 1024.f) - mean * mean;
  float rstd = rsqrtf(var + 1e-5f);
  float4 o = { (v.x - mean) * rstd, (v.y - mean) * rstd,
               (v.z - mean) * rstd, (v.w - mean) * rstd };
  ((float4*)(xln + (row << 10)))[threadIdx.x] = o;
}

// out = LN(p + q) rows of 1024, f32 out
__global__ __launch_bounds__(256) void ln_out_k(const float* __restrict__ p, const float* __restrict__ q,
                                                float* __restrict__ out) {
  __shared__ float sbuf[8];
  const long row = blockIdx.x;
  float4 v = ((const float4*)(p + (row << 10)))[threadIdx.x];
  float4 u = ((const float4*)(q + (row << 10)))[threadIdx.x];
  v.x += u.x; v.y += u.y; v.z += u.z; v.w += u.w;
  float2 t = block_sum2(v.x + v.y + v.z + v.w,
                        v.x * v.x + v.y * v.y + v.z * v.z + v.w * v.w, sbuf);
  float mean = t.x * (1.f / 1024.f);
  float var  = t.y * (1.f / 1024.f) - mean * mean;
  float rstd = rsqrtf(var + 1e-5f);
  float4 o = { (v.x - mean) * rstd, (v.y - mean) * rstd,
               (v.z - mean) * rstd, (v.w - mean) * rstd };
  ((float4*)(out + (row << 10)))[threadIdx.x] = o;
}

// ---------------- exact f32 pre-projection (LDS-tiled) ----------------
__global__ __launch_bounds__(256) void pre_gemm_k(const float* __restrict__ xln,
                                                  const float* __restrict__ pw,
                                                  const float* __restrict__ pb,
                                                  float* __restrict__ pre) {
  __shared__ __align__(16) float xs[32][128];
  const int t0 = blockIdx.x * 32;
  const int m  = threadIdx.x & 63;
  const int tg = threadIdx.x >> 6;          // 0..3
  float acc[8];
#pragma unroll
  for (int i = 0; i < 8; i++) acc[i] = 0.f;

  for (int kc = 0; kc < 1024; kc += 128) {
    __syncthreads();
#pragma unroll
    for (int r = 0; r < 4; ++r) {
      int idx  = threadIdx.x + 256 * r;
      int row  = idx >> 5;
      int col4 = idx & 31;
      ((float4*)xs[row])[col4] = ((const float4*)(xln + (long)(t0 + row) * 1024 + kc))[col4];
    }
    __syncthreads();
    const float4* wrow4 = (const float4*)(pw + (long)m * 1024 + kc);
#pragma unroll 8
    for (int k4 = 0; k4 < 32; ++k4) {
      float4 w4 = wrow4[k4];
#pragma unroll
      for (int tt = 0; tt < 8; ++tt) {
        float4 xv = ((const float4*)xs[tg * 8 + tt])[k4];
        acc[tt] += w4.x * xv.x + w4.y * xv.y + w4.z * xv.z + w4.w * xv.w;
      }
    }
  }
  const float bias = pb[m];
#pragma unroll
  for (int tt = 0; tt < 8; ++tt) {
    float v = acc[tt] + bias;
    float sp = fmaxf(v, 0.f) + log1pf(expf(-fabsf(v)));
    pre[(long)(t0 + tg * 8 + tt) * 64 + m] = sp;
  }
}

// ---------------- chunked complex reset-scan (f64 internal) ----------------
__global__ __launch_bounds__(256) void scan_p1(const float* __restrict__ pre, const int* __restrict__ start,
                                               const float* __restrict__ a, const float* __restrict__ bfr,
                                               double2* __restrict__ chA, double2* __restrict__ chB) {
  int ch = blockIdx.y * 256 + threadIdx.x;
  int m = ch >> 4, c = ch & 15;
  double dec = exp(-fabs((double)a[m]));
  double th = (double)bfr[c];
  double gre = dec * cos(th), gim = dec * sin(th);
  int j = blockIdx.x;
  int t0 = j * CHUNK;
  double pr = 1.0, pi = 0.0, sr = 0.0, si = 0.0;
  for (int t = t0; t < t0 + CHUNK; ++t) {
    double b = (double)pre[(long)t * 64 + m];
    if (start[t]) {
      pr = 0.0; pi = 0.0; sr = b; si = 0.0;
    } else {
      double nsr = gre * sr - gim * si + b;
      si = gre * si + gim * sr; sr = nsr;
      double npr = gre * pr - gim * pi;
      pi = gre * pi + gim * pr; pr = npr;
    }
  }
  chA[j * MC + ch] = make_double2(pr, pi);
  chB[j * MC + ch] = make_double2(sr, si);
}

// composes chunks: per-chunk carry, zeroes red, writes the final-state tail.
__global__ __launch_bounds__(256) void scan_p2(const double2* __restrict__ chA, const double2* __restrict__ chB,
                                               const float* __restrict__ state0,
                                               double2* __restrict__ carry, double* __restrict__ red,
                                               float* __restrict__ out_tail, int fmt) {
  if (blockIdx.x == 0 && threadIdx.x < 4) red[threadIdx.x] = 0.0;
  int ch = blockIdx.x * 256 + threadIdx.x;
  double cr = (double)state0[ch], ci = 0.0;
  for (int j = 0; j < NCH; ++j) {
    carry[j * MC + ch] = make_double2(cr, ci);
    double2 A = chA[j * MC + ch];
    double2 B = chB[j * MC + ch];
    double ncr = A.x * cr - A.y * ci + B.x;
    ci = A.x * ci + A.y * cr + B.y;
    cr = ncr;
  }
  if (fmt == 1024) {
    out_tail[ch] = (float)cr;
  } else {
    out_tail[2 * ch]     = (float)cr;
    out_tail[2 * ch + 1] = (float)ci;
  }
}

// reduction-only replay (no sz materialization)
__global__ __launch_bounds__(256) void scan_p3(const float* __restrict__ pre, const int* __restrict__ start,
                                               const float* __restrict__ a, const float* __restrict__ bfr,
                                               const double2* __restrict__ carry,
                                               double* __restrict__ red) {
  __shared__ double sbuf[12];
  int ch = blockIdx.y * 256 + threadIdx.x;
  int m = ch >> 4, c = ch & 15;
  double dec = exp(-fabs((double)a[m]));
  double th = (double)bfr[c];
  double gre = dec * cos(th), gim = dec * sin(th);
  int j = blockIdx.x;
  int t0 = j * CHUNK;
  double2 cin = carry[j * MC + ch];
  double sr = cin.x, si = cin.y;
  double aR = 0.0, aI = 0.0, aS = 0.0;
  for (int t = t0; t < t0 + CHUNK; ++t) {
    double b = (double)pre[(long)t * 64 + m];
    if (start[t]) { sr = b; si = 0.0; }
    else {
      double nsr = gre * sr - gim * si + b;
      si = gre * si + gim * sr; sr = nsr;
    }
    aR += sr; aI += si; aS += sr * sr + si * si;
  }
#pragma unroll
  for (int off = 32; off > 0; off >>= 1) {
    aR += __shfl_down(aR, off); aI += __shfl_down(aI, off); aS += __shfl_down(aS, off);
  }
  if ((threadIdx.x & 63) == 0) {
    int w = threadIdx.x >> 6;
    sbuf[w * 3] = aR; sbuf[w * 3 + 1] = aI; sbuf[w * 3 + 2] = aS;
  }
  __syncthreads();
  if (threadIdx.x == 0) {
    atomicAdd(&red[0], sbuf[0] + sbuf[3] + sbuf[6] + sbuf[9]);
    atomicAdd(&red[1], sbuf[1] + sbuf[4] + sbuf[7] + sbuf[10]);
    atomicAdd(&red[2], sbuf[2] + sbuf[5] + sbuf[8] + sbuf[11]);
  }
}

__global__ void finalize_red(const double* __restrict__ red, float* __restrict__ redf) {
  const double n = (double)T_ * (double)MC;
  double mre = red[0] / n, mim = red[1] / n;
  double var = red[2] / n - mre * mre - mim * mim;
  double sd = sqrt(var > 0.0 ? var : 0.0);
  redf[0] = (float)mre;
  redf[1] = (float)mim;
  redf[2] = (float)(1.0 / (1e-6 + sd));
}

// replay scan again AFTER finalize_red; write normalized bf16 z directly.
// z[t,0:1024] = (re-mre)*inv, z[t,1024:2048] = (im-mim)*inv
__global__ __launch_bounds__(256) void zscan_k(const float* __restrict__ pre, const int* __restrict__ start,
                                               const float* __restrict__ a, const float* __restrict__ bfr,
                                               const double2* __restrict__ carry, const float* __restrict__ redf,
                                               unsigned short* __restrict__ z) {
  int ch = blockIdx.y * 256 + threadIdx.x;
  int m = ch >> 4, c = ch & 15;
  double dec = exp(-fabs((double)a[m]));
  double th = (double)bfr[c];
  double gre = dec * cos(th), gim = dec * sin(th);
  int j = blockIdx.x;
  int t0 = j * CHUNK;
  double2 cin = carry[j * MC + ch];
  double sr = cin.x, si = cin.y;
  const float mre = redf[0], mim = redf[1], inv = redf[2];
  for (int t = t0; t < t0 + CHUNK; ++t) {
    double b = (double)pre[(long)t * 64 + m];
    if (start[t]) { sr = b; si = 0.0; }
    else {
      double nsr = gre * sr - gim * si + b;
      si = gre * si + gim * sr; sr = nsr;
    }
    z[(long)t * 2048 + ch]        = f2bf(((float)sr - mre) * inv);
    z[(long)t * 2048 + 1024 + ch] = f2bf(((float)si - mim) * inv);
  }
}

// ---------------- bf16 MFMA GEMM (m97 structure + source-side LDS XOR swizzle) ----------------
// C[t,o] = sum_k A[t,k]*B[o,k] + bias[o].  EP: 0 = f32 out, 2 = mish bf16 out.
// Swizzle (rule #21: linear LDS dest via global_load_lds + inverse-swizzled SOURCE + swizzled READ):
//   LDS[row][slot] holds global[row][slot ^ ((row>>1)&3)]  (slot = 16B segment of the 64B row)
//   reader of K-quarter q reads slot q ^ ((row>>1)&3)  -> 16-lane groups spread over 8 bank-segments (2-way, free)
template<int EP>
__global__ __launch_bounds__(256) void gemm_bt(const unsigned short* __restrict__ A,
                                               const unsigned short* __restrict__ B,
                                               const float* __restrict__ bias, void* __restrict__ Cout,
                                               int M_, int N_, int K_) {
  __shared__ __align__(16) unsigned short lA[128 * 32];
  __shared__ __align__(16) unsigned short lB[128 * 32];
  const int tid = threadIdx.x;
  const int lane = tid & 63;
  const int wv = tid >> 6;
  const int wr = wv >> 1, wc = wv & 1;
  const long brow = (long)blockIdx.x * 128;
  const long bcol = (long)blockIdx.y * 128;

  f32x4 acc[4][4];
#pragma unroll
  for (int i = 0; i < 4; i++)
#pragma unroll
    for (int j = 0; j < 4; j++)
      acc[i][j] = f32x4{0.f, 0.f, 0.f, 0.f};

  const int c0 = tid, c1 = tid + 256;
  const long ar0 = brow + (c0 >> 2), ar1 = brow + (c1 >> 2);
  const long br0 = bcol + (c0 >> 2), br1 = bcol + (c1 >> 2);
  // inverse-swizzled source slot: (c&3) ^ ((row>>1)&3) = (c&3) ^ ((c>>3)&3)
  const int ko0 = (((c0 & 3) ^ ((c0 >> 3) & 3)) * 8);
  const int ko1 = (((c1 & 3) ^ ((c1 >> 3) & 3)) * 8);
  const int r15 = lane & 15;
  // swizzled read slot: q ^ ((row>>1)&3) = (lane>>4) ^ ((r15>>1)&3)  (row%16 == r15 here)
  const int swzq = (((lane >> 4) ^ ((r15 >> 1) & 3)) * 8);

  for (int kt = 0; kt < K_; kt += 32) {
    __syncthreads();
    gload_lds16(A + ar0 * K_ + kt + ko0, &lA[c0 * 8]);
    gload_lds16(A + ar1 * K_ + kt + ko1, &lA[c1 * 8]);
    gload_lds16(B + br0 * K_ + kt + ko0, &lB[c0 * 8]);
    gload_lds16(B + br1 * K_ + kt + ko1, &lB[c1 * 8]);
    asm volatile("s_waitcnt vmcnt(0)" ::: "memory");
    __syncthreads();
    bf16x8 af[4], bv[4];
#pragma unroll
    for (int mi = 0; mi < 4; mi++)
      af[mi] = *(const bf16x8*)&lA[(wr * 64 + mi * 16 + r15) * 32 + swzq];
#pragma unroll
    for (int nj = 0; nj < 4; nj++)
      bv[nj] = *(const bf16x8*)&lB[(wc * 64 + nj * 16 + r15) * 32 + swzq];
#pragma unroll
    for (int mi = 0; mi < 4; mi++)
#pragma unroll
      for (int nj = 0; nj < 4; nj++)
        acc[mi][nj] = __builtin_amdgcn_mfma_f32_16x16x32_bf16(af[mi], bv[nj], acc[mi][nj], 0, 0, 0);
  }

  const int rq = (lane >> 4) * 4;
#pragma unroll
  for (int nj = 0; nj < 4; nj++) {
    const long col = bcol + wc * 64 + nj * 16 + r15;
    const float bs = bias[col];
#pragma unroll
    for (int mi = 0; mi < 4; mi++) {
#pragma unroll
      for (int r = 0; r < 4; r++) {
        const long row = brow + wr * 64 + mi * 16 + rq + r;
        float v = acc[mi][nj][r] + bs;
        if (EP == 0) {
          ((float*)Cout)[row * N_ + col] = v;
        } else {
          ((unsigned short*)Cout)[row * N_ + col] = f2bf(mish_f(v));
        }
      }
    }
  }
}

// ---------------- host-side orchestration ----------------
extern "C" void kernel_launch(void* const* d_in, const int* in_sizes, int n_in,
                              void* d_out, int out_size, void* d_ws, size_t ws_size,
                              hipStream_t stream) {
  (void)in_sizes; (void)n_in; (void)ws_size;
  const float* x      = (const float*)d_in[0];
  const float* state0 = (const float*)d_in[1];
  const int*   start  = (const int*)d_in[2];
  const float* a      = (const float*)d_in[4];
  const float* bfr    = (const float*)d_in[5];
  const float* pre_w  = (const float*)d_in[6];
  const float* pre_b  = (const float*)d_in[7];
  const float* skip_w = (const float*)d_in[8];
  const float* skip_b = (const float*)d_in[9];
  const float* w1     = (const float*)d_in[10];
  const float* b1     = (const float*)d_in[11];
  const float* w2     = (const float*)d_in[12];
  const float* b2     = (const float*)d_in[13];
  const float* w3     = (const float*)d_in[14];
  const float* b3     = (const float*)d_in[15];

  char* ws = (char*)d_ws;
  const size_t MB = 1u << 20;
  float*          xlnf  = (float*)(ws + 0);          // dead after pre_gemm
  float*          skipf = (float*)(ws + 0);          // written by skip GEMM (after pre_gemm)
  float*          h3    = (float*)(ws + 32 * MB);
  unsigned short* z     = (unsigned short*)(ws + 64 * MB);
  unsigned short* xb    = (unsigned short*)(ws + 96 * MB);   // reused as h2 after skip GEMM consumed xb
  unsigned short* h2    = (unsigned short*)(ws + 96 * MB);
  unsigned short* h1    = (unsigned short*)(ws + 112 * MB);
  unsigned short* wb1   = (unsigned short*)(ws + 128 * MB);
  unsigned short* wb2   = (unsigned short*)(ws + 132 * MB);
  unsigned short* wb3   = (unsigned short*)(ws + 134 * MB);
  unsigned short* skwb  = (unsigned short*)(ws + 136 * MB);
  float*          pre   = (float*)(ws + 138 * MB);
  double2*        chA   = (double2*)(ws + 140 * MB);
  double2*        chB   = (double2*)(ws + 142 * MB);
  double2*        carry = (double2*)(ws + 144 * MB);
  double*         red   = (double*)(ws + 146 * MB);
  float*          redf  = (float*)(ws + 146 * MB + 64);

  // 1) weight casts for the big GEMMs
  cast_f32_bf16<<<2048, 256, 0, stream>>>(w1, wb1, 2097152);
  cast_f32_bf16<<<1024, 256, 0, stream>>>(w2, wb2, 1048576);
  cast_f32_bf16<<<1024, 256, 0, stream>>>(w3, wb3, 1048576);
  cast_f32_bf16<<<1024, 256, 0, stream>>>(skip_w, skwb, 1048576);

  // 2) fused: xln = LN(x) (f32) + xb = bf16(x); then exact f32 pre-projection (LDS-tiled)
  ln_cast_k<<<8192, 256, 0, stream>>>(x, xlnf, xb);
  pre_gemm_k<<<256, 256, 0, stream>>>(xlnf, pre_w, pre_b, pre);

  // 3) chunked scan; p2 composes carries and writes the final-state tail directly
  int tail_elems = out_size - T_ * NOUT;          // 1024 (real only) or 2048 (interleaved)
  float* out_tail = (float*)d_out + (long)T_ * NOUT;
  scan_p1<<<dim3(NCH, 4), 256, 0, stream>>>(pre, start, a, bfr, chA, chB);
  scan_p2<<<4, 256, 0, stream>>>(chA, chB, state0, carry, red, out_tail, tail_elems);
  scan_p3<<<dim3(NCH, 4), 256, 0, stream>>>(pre, start, a, bfr, carry, red);
  finalize_red<<<1, 1, 0, stream>>>(red, redf);

  // 4) replay scan -> normalized bf16 z (no sz materialization)
  zscan_k<<<dim3(NCH, 4), 256, 0, stream>>>(pre, start, a, bfr, carry, redf, z);

  // 5) skip GEMM, then the 3-layer mish MLP
  gemm_bt<0><<<dim3(64, 8), 256, 0, stream>>>(xb, skwb, skip_b, skipf, T_, 1024, 1024);
  gemm_bt<2><<<dim3(64, 8), 256, 0, stream>>>(z,  wb1, b1, h1, T_, 1024, 2048);
  gemm_bt<2><<<dim3(64, 8), 256, 0, stream>>>(h1, wb2, b2, h2, T_, 1024, 1024);
  gemm_bt<0><<<dim3(64, 8), 256, 0, stream>>>(h2, wb3, b3, h3, T_, 1024, 1024);

  // 6) out = LN(h3 + skip)
  ln_out_k<<<8192, 256, 0, stream>>>(h3, skipf, (float*)d_out);
}

// Round 7
// 324.701 us; speedup vs baseline: 3.7037x; 1.0685x over previous
//
#include <hip/hip_runtime.h>
#include <hip/hip_bf16.h>

// ---------------- problem constants ----------------
#define T_    8192
#define INDIM 1024
#define MTR   64
#define CCTX  16
#define MC    1024     // MTR*CCTX
#define NOUT  1024
#define CHUNK 64
#define NCH   128      // T_/CHUNK

using bf16x8 = __attribute__((ext_vector_type(8))) short;
using f32x4  = __attribute__((ext_vector_type(4))) float;

__device__ __forceinline__ unsigned short f2bf(float f) {
  unsigned int u = __builtin_bit_cast(unsigned int, f);
  u += 0x7fffu + ((u >> 16) & 1u);
  return (unsigned short)(u >> 16);
}

// cheap mish: v * tanh(softplus(v)) = v * w/(w+2), w = e^v*(e^v+2); v>20 -> v
__device__ __forceinline__ float mish_f(float v) {
  float u = __expf(v);
  float w = u * (u + 2.f);
  return (v > 20.f) ? v : v * __fdividef(w, w + 2.f);
}

typedef __attribute__((address_space(1))) void gas_void;
typedef __attribute__((address_space(3))) void las_void;

__device__ __forceinline__ void gload_lds16(const void* g, void* l) {
  __builtin_amdgcn_global_load_lds((gas_void*)g, (las_void*)l, 16, 0, 0);
}

// ---------------- elementwise / cast kernels ----------------
__global__ __launch_bounds__(256) void cast_f32_bf16(const float* __restrict__ src,
                                                     unsigned short* __restrict__ dst, long n) {
  long i = ((long)blockIdx.x * 256 + threadIdx.x) * 4;
  if (i >= n) return;
  float4 v = *(const float4*)(src + i);
  ushort4 o = { f2bf(v.x), f2bf(v.y), f2bf(v.z), f2bf(v.w) };
  *(ushort4*)(dst + i) = o;
}

__device__ __forceinline__ float2 block_sum2(float s, float ss, float* sbuf) {
#pragma unroll
  for (int off = 32; off > 0; off >>= 1) {
    s  += __shfl_down(s, off);
    ss += __shfl_down(ss, off);
  }
  if ((threadIdx.x & 63) == 0) {
    sbuf[(threadIdx.x >> 6) * 2]     = s;
    sbuf[(threadIdx.x >> 6) * 2 + 1] = ss;
  }
  __syncthreads();
  return make_float2(sbuf[0] + sbuf[2] + sbuf[4] + sbuf[6],
                     sbuf[1] + sbuf[3] + sbuf[5] + sbuf[7]);
}

// LayerNorm(x) rows of 1024 f32 -> f32 xln (exact pre path) + bf16 cast of raw x (skip GEMM input)
__global__ __launch_bounds__(256) void ln_cast_k(const float* __restrict__ x,
                                                 float* __restrict__ xln,
                                                 unsigned short* __restrict__ xb) {
  __shared__ float sbuf[8];
  const long row = blockIdx.x;
  float4 v = ((const float4*)(x + (row << 10)))[threadIdx.x];
  ushort4 c = { f2bf(v.x), f2bf(v.y), f2bf(v.z), f2bf(v.w) };
  ((ushort4*)(xb + (row << 10)))[threadIdx.x] = c;
  float2 t = block_sum2(v.x + v.y + v.z + v.w,
                        v.x * v.x + v.y * v.y + v.z * v.z + v.w * v.w, sbuf);
  float mean = t.x * (1.f / 1024.f);
  float var  = t.y * (1.f / 1024.f) - mean * mean;
  float rstd = rsqrtf(var + 1e-5f);
  float4 o = { (v.x - mean) * rstd, (v.y - mean) * rstd,
               (v.z - mean) * rstd, (v.w - mean) * rstd };
  ((float4*)(xln + (row << 10)))[threadIdx.x] = o;
}

// out = LN(p + q) rows of 1024, f32 out
__global__ __launch_bounds__(256) void ln_out_k(const float* __restrict__ p, const float* __restrict__ q,
                                                float* __restrict__ out) {
  __shared__ float sbuf[8];
  const long row = blockIdx.x;
  float4 v = ((const float4*)(p + (row << 10)))[threadIdx.x];
  float4 u = ((const float4*)(q + (row << 10)))[threadIdx.x];
  v.x += u.x; v.y += u.y; v.z += u.z; v.w += u.w;
  float2 t = block_sum2(v.x + v.y + v.z + v.w,
                        v.x * v.x + v.y * v.y + v.z * v.z + v.w * v.w, sbuf);
  float mean = t.x * (1.f / 1024.f);
  float var  = t.y * (1.f / 1024.f) - mean * mean;
  float rstd = rsqrtf(var + 1e-5f);
  float4 o = { (v.x - mean) * rstd, (v.y - mean) * rstd,
               (v.z - mean) * rstd, (v.w - mean) * rstd };
  ((float4*)(out + (row << 10)))[threadIdx.x] = o;
}

// ---------------- exact f32 pre-projection, register-weights + scalar-x ----------------
// grid (64, 8): block x = row-block (4 waves x 32 rows), block y = kc (K/8 split of 128).
// lane = m: weight slice w[lane][kc*128..+128] lives in 128 VGPRs (loaded once).
// x row chunks are wave-uniform -> readfirstlane'd base => s_load on the scalar pipe.
// partial dot -> part[kc][t][m]; pre_fin_k sums 8 parts + bias + softplus.
__global__ __launch_bounds__(256) void pre_part_k(const float* __restrict__ xln,
                                                  const float* __restrict__ pw,
                                                  float* __restrict__ part) {
  const int lane = threadIdx.x & 63;
  const int wvu  = __builtin_amdgcn_readfirstlane(threadIdx.x >> 6);  // uniform wave id -> s_load path
  const int kc   = blockIdx.y;
  const int r0   = (blockIdx.x * 4 + wvu) * 32;

  const float* wrow = pw + (long)lane * 1024 + kc * 128;
  float wreg[128];
#pragma unroll
  for (int j = 0; j < 32; ++j)
    *(float4*)&wreg[j * 4] = ((const float4*)wrow)[j];

  float* po = part + ((long)kc * T_ + r0) * 64 + lane;
  const float* xbase = xln + (long)r0 * 1024 + kc * 128;

  for (int i = 0; i < 32; i += 2) {
    const float4* xr0 = (const float4*)(xbase + (long)i * 1024);
    const float4* xr1 = (const float4*)(xbase + (long)(i + 1) * 1024);
    float a0 = 0.f, a1 = 0.f, a2 = 0.f, a3 = 0.f;
    float b0 = 0.f, b1 = 0.f, b2 = 0.f, b3 = 0.f;
#pragma unroll
    for (int j = 0; j < 32; j += 4) {
      float4 xa0 = xr0[j],     xa1 = xr0[j + 1], xa2 = xr0[j + 2], xa3 = xr0[j + 3];
      float4 xb0 = xr1[j],     xb1 = xr1[j + 1], xb2 = xr1[j + 2], xb3 = xr1[j + 3];
      a0 += wreg[4*j+0]*xa0.x  + wreg[4*j+1]*xa0.y  + wreg[4*j+2]*xa0.z  + wreg[4*j+3]*xa0.w;
      a1 += wreg[4*j+4]*xa1.x  + wreg[4*j+5]*xa1.y  + wreg[4*j+6]*xa1.z  + wreg[4*j+7]*xa1.w;
      a2 += wreg[4*j+8]*xa2.x  + wreg[4*j+9]*xa2.y  + wreg[4*j+10]*xa2.z + wreg[4*j+11]*xa2.w;
      a3 += wreg[4*j+12]*xa3.x + wreg[4*j+13]*xa3.y + wreg[4*j+14]*xa3.z + wreg[4*j+15]*xa3.w;
      b0 += wreg[4*j+0]*xb0.x  + wreg[4*j+1]*xb0.y  + wreg[4*j+2]*xb0.z  + wreg[4*j+3]*xb0.w;
      b1 += wreg[4*j+4]*xb1.x  + wreg[4*j+5]*xb1.y  + wreg[4*j+6]*xb1.z  + wreg[4*j+7]*xb1.w;
      b2 += wreg[4*j+8]*xb2.x  + wreg[4*j+9]*xb2.y  + wreg[4*j+10]*xb2.z + wreg[4*j+11]*xb2.w;
      b3 += wreg[4*j+12]*xb3.x + wreg[4*j+13]*xb3.y + wreg[4*j+14]*xb3.z + wreg[4*j+15]*xb3.w;
    }
    po[(long)i * 64]       = (a0 + a1) + (a2 + a3);
    po[(long)(i + 1) * 64] = (b0 + b1) + (b2 + b3);
  }
}

// pre[t,m] = softplus(sum_kc part[kc][t][m] + pb[m])
__global__ __launch_bounds__(256) void pre_fin_k(const float* __restrict__ part,
                                                 const float* __restrict__ pb,
                                                 float* __restrict__ pre) {
  long i = (long)blockIdx.x * 256 + threadIdx.x;   // over T_*64
  int m = (int)(i & 63);
  float s = 0.f;
#pragma unroll
  for (int kc = 0; kc < 8; ++kc)
    s += part[(long)kc * T_ * 64 + i];
  float v = s + pb[m];
  float sp = fmaxf(v, 0.f) + log1pf(expf(-fabsf(v)));
  pre[i] = sp;
}

// ---------------- chunked complex reset-scan (f64 internal) ----------------
__global__ __launch_bounds__(256) void scan_p1(const float* __restrict__ pre, const int* __restrict__ start,
                                               const float* __restrict__ a, const float* __restrict__ bfr,
                                               double2* __restrict__ chA, double2* __restrict__ chB) {
  int ch = blockIdx.y * 256 + threadIdx.x;
  int m = ch >> 4, c = ch & 15;
  double dec = exp(-fabs((double)a[m]));
  double th = (double)bfr[c];
  double gre = dec * cos(th), gim = dec * sin(th);
  int j = blockIdx.x;
  int t0 = j * CHUNK;
  double pr = 1.0, pi = 0.0, sr = 0.0, si = 0.0;
  for (int t = t0; t < t0 + CHUNK; ++t) {
    double b = (double)pre[(long)t * 64 + m];
    if (start[t]) {
      pr = 0.0; pi = 0.0; sr = b; si = 0.0;
    } else {
      double nsr = gre * sr - gim * si + b;
      si = gre * si + gim * sr; sr = nsr;
      double npr = gre * pr - gim * pi;
      pi = gre * pi + gim * pr; pr = npr;
    }
  }
  chA[j * MC + ch] = make_double2(pr, pi);
  chB[j * MC + ch] = make_double2(sr, si);
}

// composes chunks: per-chunk carry, zeroes red, writes the final-state tail.
__global__ __launch_bounds__(256) void scan_p2(const double2* __restrict__ chA, const double2* __restrict__ chB,
                                               const float* __restrict__ state0,
                                               double2* __restrict__ carry, double* __restrict__ red,
                                               float* __restrict__ out_tail, int fmt) {
  if (blockIdx.x == 0 && threadIdx.x < 4) red[threadIdx.x] = 0.0;
  int ch = blockIdx.x * 256 + threadIdx.x;
  double cr = (double)state0[ch], ci = 0.0;
  for (int j = 0; j < NCH; ++j) {
    carry[j * MC + ch] = make_double2(cr, ci);
    double2 A = chA[j * MC + ch];
    double2 B = chB[j * MC + ch];
    double ncr = A.x * cr - A.y * ci + B.x;
    ci = A.x * ci + A.y * cr + B.y;
    cr = ncr;
  }
  if (fmt == 1024) {
    out_tail[ch] = (float)cr;
  } else {
    out_tail[2 * ch]     = (float)cr;
    out_tail[2 * ch + 1] = (float)ci;
  }
}

// reduction-only replay (no sz materialization)
__global__ __launch_bounds__(256) void scan_p3(const float* __restrict__ pre, const int* __restrict__ start,
                                               const float* __restrict__ a, const float* __restrict__ bfr,
                                               const double2* __restrict__ carry,
                                               double* __restrict__ red) {
  __shared__ double sbuf[12];
  int ch = blockIdx.y * 256 + threadIdx.x;
  int m = ch >> 4, c = ch & 15;
  double dec = exp(-fabs((double)a[m]));
  double th = (double)bfr[c];
  double gre = dec * cos(th), gim = dec * sin(th);
  int j = blockIdx.x;
  int t0 = j * CHUNK;
  double2 cin = carry[j * MC + ch];
  double sr = cin.x, si = cin.y;
  double aR = 0.0, aI = 0.0, aS = 0.0;
  for (int t = t0; t < t0 + CHUNK; ++t) {
    double b = (double)pre[(long)t * 64 + m];
    if (start[t]) { sr = b; si = 0.0; }
    else {
      double nsr = gre * sr - gim * si + b;
      si = gre * si + gim * sr; sr = nsr;
    }
    aR += sr; aI += si; aS += sr * sr + si * si;
  }
#pragma unroll
  for (int off = 32; off > 0; off >>= 1) {
    aR += __shfl_down(aR, off); aI += __shfl_down(aI, off); aS += __shfl_down(aS, off);
  }
  if ((threadIdx.x & 63) == 0) {
    int w = threadIdx.x >> 6;
    sbuf[w * 3] = aR; sbuf[w * 3 + 1] = aI; sbuf[w * 3 + 2] = aS;
  }
  __syncthreads();
  if (threadIdx.x == 0) {
    atomicAdd(&red[0], sbuf[0] + sbuf[3] + sbuf[6] + sbuf[9]);
    atomicAdd(&red[1], sbuf[1] + sbuf[4] + sbuf[7] + sbuf[10]);
    atomicAdd(&red[2], sbuf[2] + sbuf[5] + sbuf[8] + sbuf[11]);
  }
}

__global__ void finalize_red(const double* __restrict__ red, float* __restrict__ redf) {
  const double n = (double)T_ * (double)MC;
  double mre = red[0] / n, mim = red[1] / n;
  double var = red[2] / n - mre * mre - mim * mim;
  double sd = sqrt(var > 0.0 ? var : 0.0);
  redf[0] = (float)mre;
  redf[1] = (float)mim;
  redf[2] = (float)(1.0 / (1e-6 + sd));
}

// replay scan AFTER finalize_red; write normalized bf16 z directly.
__global__ __launch_bounds__(256) void zscan_k(const float* __restrict__ pre, const int* __restrict__ start,
                                               const float* __restrict__ a, const float* __restrict__ bfr,
                                               const double2* __restrict__ carry, const float* __restrict__ redf,
                                               unsigned short* __restrict__ z) {
  int ch = blockIdx.y * 256 + threadIdx.x;
  int m = ch >> 4, c = ch & 15;
  double dec = exp(-fabs((double)a[m]));
  double th = (double)bfr[c];
  double gre = dec * cos(th), gim = dec * sin(th);
  int j = blockIdx.x;
  int t0 = j * CHUNK;
  double2 cin = carry[j * MC + ch];
  double sr = cin.x, si = cin.y;
  const float mre = redf[0], mim = redf[1], inv = redf[2];
  for (int t = t0; t < t0 + CHUNK; ++t) {
    double b = (double)pre[(long)t * 64 + m];
    if (start[t]) { sr = b; si = 0.0; }
    else {
      double nsr = gre * sr - gim * si + b;
      si = gre * si + gim * sr; sr = nsr;
    }
    z[(long)t * 2048 + ch]        = f2bf(((float)sr - mre) * inv);
    z[(long)t * 2048 + 1024 + ch] = f2bf(((float)si - mim) * inv);
  }
}

// ---------------- bf16 MFMA GEMM (m97 structure + source-side LDS XOR swizzle) ----------------
template<int EP>
__global__ __launch_bounds__(256) void gemm_bt(const unsigned short* __restrict__ A,
                                               const unsigned short* __restrict__ B,
                                               const float* __restrict__ bias, void* __restrict__ Cout,
                                               int M_, int N_, int K_) {
  __shared__ __align__(16) unsigned short lA[128 * 32];
  __shared__ __align__(16) unsigned short lB[128 * 32];
  const int tid = threadIdx.x;
  const int lane = tid & 63;
  const int wv = tid >> 6;
  const int wr = wv >> 1, wc = wv & 1;
  const long brow = (long)blockIdx.x * 128;
  const long bcol = (long)blockIdx.y * 128;

  f32x4 acc[4][4];
#pragma unroll
  for (int i = 0; i < 4; i++)
#pragma unroll
    for (int j = 0; j < 4; j++)
      acc[i][j] = f32x4{0.f, 0.f, 0.f, 0.f};

  const int c0 = tid, c1 = tid + 256;
  const long ar0 = brow + (c0 >> 2), ar1 = brow + (c1 >> 2);
  const long br0 = bcol + (c0 >> 2), br1 = bcol + (c1 >> 2);
  const int ko0 = (((c0 & 3) ^ ((c0 >> 3) & 3)) * 8);
  const int ko1 = (((c1 & 3) ^ ((c1 >> 3) & 3)) * 8);
  const int r15 = lane & 15;
  const int swzq = (((lane >> 4) ^ ((r15 >> 1) & 3)) * 8);

  for (int kt = 0; kt < K_; kt += 32) {
    __syncthreads();
    gload_lds16(A + ar0 * K_ + kt + ko0, &lA[c0 * 8]);
    gload_lds16(A + ar1 * K_ + kt + ko1, &lA[c1 * 8]);
    gload_lds16(B + br0 * K_ + kt + ko0, &lB[c0 * 8]);
    gload_lds16(B + br1 * K_ + kt + ko1, &lB[c1 * 8]);
    asm volatile("s_waitcnt vmcnt(0)" ::: "memory");
    __syncthreads();
    bf16x8 af[4], bv[4];
#pragma unroll
    for (int mi = 0; mi < 4; mi++)
      af[mi] = *(const bf16x8*)&lA[(wr * 64 + mi * 16 + r15) * 32 + swzq];
#pragma unroll
    for (int nj = 0; nj < 4; nj++)
      bv[nj] = *(const bf16x8*)&lB[(wc * 64 + nj * 16 + r15) * 32 + swzq];
#pragma unroll
    for (int mi = 0; mi < 4; mi++)
#pragma unroll
      for (int nj = 0; nj < 4; nj++)
        acc[mi][nj] = __builtin_amdgcn_mfma_f32_16x16x32_bf16(af[mi], bv[nj], acc[mi][nj], 0, 0, 0);
  }

  const int rq = (lane >> 4) * 4;
#pragma unroll
  for (int nj = 0; nj < 4; nj++) {
    const long col = bcol + wc * 64 + nj * 16 + r15;
    const float bs = bias[col];
#pragma unroll
    for (int mi = 0; mi < 4; mi++) {
#pragma unroll
      for (int r = 0; r < 4; r++) {
        const long row = brow + wr * 64 + mi * 16 + rq + r;
        float v = acc[mi][nj][r] + bs;
        if (EP == 0) {
          ((float*)Cout)[row * N_ + col] = v;
        } else {
          ((unsigned short*)Cout)[row * N_ + col] = f2bf(mish_f(v));
        }
      }
    }
  }
}

// ---------------- host-side orchestration ----------------
extern "C" void kernel_launch(void* const* d_in, const int* in_sizes, int n_in,
                              void* d_out, int out_size, void* d_ws, size_t ws_size,
                              hipStream_t stream) {
  (void)in_sizes; (void)n_in; (void)ws_size;
  const float* x      = (const float*)d_in[0];
  const float* state0 = (const float*)d_in[1];
  const int*   start  = (const int*)d_in[2];
  const float* a      = (const float*)d_in[4];
  const float* bfr    = (const float*)d_in[5];
  const float* pre_w  = (const float*)d_in[6];
  const float* pre_b  = (const float*)d_in[7];
  const float* skip_w = (const float*)d_in[8];
  const float* skip_b = (const float*)d_in[9];
  const float* w1     = (const float*)d_in[10];
  const float* b1     = (const float*)d_in[11];
  const float* w2     = (const float*)d_in[12];
  const float* b2     = (const float*)d_in[13];
  const float* w3     = (const float*)d_in[14];
  const float* b3     = (const float*)d_in[15];

  char* ws = (char*)d_ws;
  const size_t MB = 1u << 20;
  float*          xlnf  = (float*)(ws + 0);          // dead after pre_part_k
  float*          skipf = (float*)(ws + 0);          // written by skip GEMM later
  float*          part  = (float*)(ws + 32 * MB);    // 16MB [8][T][64]; dead after pre_fin_k
  float*          h3    = (float*)(ws + 32 * MB);    // written by mix3 (after part is dead)
  unsigned short* z     = (unsigned short*)(ws + 64 * MB);
  unsigned short* xb    = (unsigned short*)(ws + 96 * MB);   // reused as h2 after skip GEMM
  unsigned short* h2    = (unsigned short*)(ws + 96 * MB);
  unsigned short* h1    = (unsigned short*)(ws + 112 * MB);
  unsigned short* wb1   = (unsigned short*)(ws + 128 * MB);
  unsigned short* wb2   = (unsigned short*)(ws + 132 * MB);
  unsigned short* wb3   = (unsigned short*)(ws + 134 * MB);
  unsigned short* skwb  = (unsigned short*)(ws + 136 * MB);
  float*          pre   = (float*)(ws + 138 * MB);
  double2*        chA   = (double2*)(ws + 140 * MB);
  double2*        chB   = (double2*)(ws + 142 * MB);
  double2*        carry = (double2*)(ws + 144 * MB);
  double*         red   = (double*)(ws + 146 * MB);
  float*          redf  = (float*)(ws + 146 * MB + 64);

  // 1) weight casts for the big GEMMs
  cast_f32_bf16<<<2048, 256, 0, stream>>>(w1, wb1, 2097152);
  cast_f32_bf16<<<1024, 256, 0, stream>>>(w2, wb2, 1048576);
  cast_f32_bf16<<<1024, 256, 0, stream>>>(w3, wb3, 1048576);
  cast_f32_bf16<<<1024, 256, 0, stream>>>(skip_w, skwb, 1048576);

  // 2) fused LN+cast; then exact f32 pre-projection (register-weights, scalar-x, K-split)
  ln_cast_k<<<8192, 256, 0, stream>>>(x, xlnf, xb);
  pre_part_k<<<dim3(64, 8), 256, 0, stream>>>(xlnf, pre_w, part);
  pre_fin_k<<<2048, 256, 0, stream>>>(part, pre_b, pre);

  // 3) chunked scan; p2 composes carries and writes the final-state tail directly
  int tail_elems = out_size - T_ * NOUT;          // 1024 (real only) or 2048 (interleaved)
  float* out_tail = (float*)d_out + (long)T_ * NOUT;
  scan_p1<<<dim3(NCH, 4), 256, 0, stream>>>(pre, start, a, bfr, chA, chB);
  scan_p2<<<4, 256, 0, stream>>>(chA, chB, state0, carry, red, out_tail, tail_elems);
  scan_p3<<<dim3(NCH, 4), 256, 0, stream>>>(pre, start, a, bfr, carry, red);
  finalize_red<<<1, 1, 0, stream>>>(red, redf);

  // 4) replay scan -> normalized bf16 z (no sz materialization)
  zscan_k<<<dim3(NCH, 4), 256, 0, stream>>>(pre, start, a, bfr, carry, redf, z);

  // 5) skip GEMM, then the 3-layer mish MLP
  gemm_bt<0><<<dim3(64, 8), 256, 0, stream>>>(xb, skwb, skip_b, skipf, T_, 1024, 1024);
  gemm_bt<2><<<dim3(64, 8), 256, 0, stream>>>(z,  wb1, b1, h1, T_, 1024, 2048);
  gemm_bt<2><<<dim3(64, 8), 256, 0, stream>>>(h1, wb2, b2, h2, T_, 1024, 1024);
  gemm_bt<0><<<dim3(64, 8), 256, 0, stream>>>(h2, wb3, b3, h3, T_, 1024, 1024);

  // 6) out = LN(h3 + skip)
  ln_out_k<<<8192, 256, 0, stream>>>(h3, skipf, (float*)d_out);
}

// Round 8
// 307.799 us; speedup vs baseline: 3.9071x; 1.0549x over previous
//
#include <hip/hip_runtime.h>
#include <hip/hip_bf16.h>

// ---------------- problem constants ----------------
#define T_    8192
#define INDIM 1024
#define MTR   64
#define CCTX  16
#define MC    1024     // MTR*CCTX
#define NOUT  1024
#define CHUNK 64
#define NCH   128      // T_/CHUNK

using bf16x8 = __attribute__((ext_vector_type(8))) short;
using f32x4  = __attribute__((ext_vector_type(4))) float;

__device__ __forceinline__ unsigned short f2bf(float f) {
  unsigned int u = __builtin_bit_cast(unsigned int, f);
  u += 0x7fffu + ((u >> 16) & 1u);
  return (unsigned short)(u >> 16);
}

// cheap mish: v * tanh(softplus(v)) = v * w/(w+2), w = e^v*(e^v+2); v>20 -> v
__device__ __forceinline__ float mish_f(float v) {
  float u = __expf(v);
  float w = u * (u + 2.f);
  return (v > 20.f) ? v : v * __fdividef(w, w + 2.f);
}

typedef __attribute__((address_space(1))) void gas_void;
typedef __attribute__((address_space(3))) void las_void;

__device__ __forceinline__ void gload_lds16(const void* g, void* l) {
  __builtin_amdgcn_global_load_lds((gas_void*)g, (las_void*)l, 16, 0, 0);
}

// ---------------- merged weight casts (w1|w2|w3|skip_w) ----------------
__global__ __launch_bounds__(256) void cast4_k(const float* __restrict__ w1, const float* __restrict__ w2,
                                               const float* __restrict__ w3, const float* __restrict__ sw,
                                               unsigned short* __restrict__ o1, unsigned short* __restrict__ o2,
                                               unsigned short* __restrict__ o3, unsigned short* __restrict__ o4) {
  long i = ((long)blockIdx.x * 256 + threadIdx.x) * 4;
  const float* src; unsigned short* dst; long off;
  if (i < 2097152)      { src = w1; dst = o1; off = i; }
  else if (i < 3145728) { src = w2; dst = o2; off = i - 2097152; }
  else if (i < 4194304) { src = w3; dst = o3; off = i - 3145728; }
  else if (i < 5242880) { src = sw; dst = o4; off = i - 4194304; }
  else return;
  float4 v = *(const float4*)(src + off);
  ushort4 o = { f2bf(v.x), f2bf(v.y), f2bf(v.z), f2bf(v.w) };
  *(ushort4*)(dst + off) = o;
}

__device__ __forceinline__ float2 block_sum2(float s, float ss, float* sbuf) {
#pragma unroll
  for (int off = 32; off > 0; off >>= 1) {
    s  += __shfl_down(s, off);
    ss += __shfl_down(ss, off);
  }
  if ((threadIdx.x & 63) == 0) {
    sbuf[(threadIdx.x >> 6) * 2]     = s;
    sbuf[(threadIdx.x >> 6) * 2 + 1] = ss;
  }
  __syncthreads();
  return make_float2(sbuf[0] + sbuf[2] + sbuf[4] + sbuf[6],
                     sbuf[1] + sbuf[3] + sbuf[5] + sbuf[7]);
}

// per-row LN stats (mean, rstd) + bf16 cast of raw x. No xln materialization.
__global__ __launch_bounds__(256) void ln_cast_k(const float* __restrict__ x,
                                                 float2* __restrict__ rowstat,
                                                 unsigned short* __restrict__ xb) {
  __shared__ float sbuf[8];
  const long row = blockIdx.x;
  float4 v = ((const float4*)(x + (row << 10)))[threadIdx.x];
  ushort4 c = { f2bf(v.x), f2bf(v.y), f2bf(v.z), f2bf(v.w) };
  ((ushort4*)(xb + (row << 10)))[threadIdx.x] = c;
  float2 t = block_sum2(v.x + v.y + v.z + v.w,
                        v.x * v.x + v.y * v.y + v.z * v.z + v.w * v.w, sbuf);
  float mean = t.x * (1.f / 1024.f);
  float var  = t.y * (1.f / 1024.f) - mean * mean;
  float rstd = rsqrtf(var + 1e-5f);
  if (threadIdx.x == 0) rowstat[row] = make_float2(mean, rstd);
}

// out = LN(s) rows of 1024 (single input; skip-add already fused into mix3)
__global__ __launch_bounds__(256) void ln_out1_k(const float* __restrict__ p, float* __restrict__ out) {
  __shared__ float sbuf[8];
  const long row = blockIdx.x;
  float4 v = ((const float4*)(p + (row << 10)))[threadIdx.x];
  float2 t = block_sum2(v.x + v.y + v.z + v.w,
                        v.x * v.x + v.y * v.y + v.z * v.z + v.w * v.w, sbuf);
  float mean = t.x * (1.f / 1024.f);
  float var  = t.y * (1.f / 1024.f) - mean * mean;
  float rstd = rsqrtf(var + 1e-5f);
  float4 o = { (v.x - mean) * rstd, (v.y - mean) * rstd,
               (v.z - mean) * rstd, (v.w - mean) * rstd };
  ((float4*)(out + (row << 10)))[threadIdx.x] = o;
}

// ---------------- f32 pre-projection: register-weights, LN applied algebraically ----------------
// dot(w, LN(x_row)) = rstd*dot(w, x_row) - mean*rstd*sum(w)   (per kc-slice)
__global__ __launch_bounds__(256) void pre_part_k(const float* __restrict__ x,
                                                  const float2* __restrict__ rowstat,
                                                  const float* __restrict__ pw,
                                                  float* __restrict__ part) {
  const int lane = threadIdx.x & 63;
  const int wvu  = __builtin_amdgcn_readfirstlane(threadIdx.x >> 6);
  const int kc   = blockIdx.y;
  const int r0   = (blockIdx.x * 4 + wvu) * 32;

  const float* wrow = pw + (long)lane * 1024 + kc * 128;
  float wreg[128];
#pragma unroll
  for (int j = 0; j < 32; ++j)
    *(float4*)&wreg[j * 4] = ((const float4*)wrow)[j];
  float swsum = 0.f;
#pragma unroll
  for (int j = 0; j < 128; ++j) swsum += wreg[j];

  float* po = part + ((long)kc * T_ + r0) * 64 + lane;
  const float* xbase = x + (long)r0 * 1024 + kc * 128;

  for (int i = 0; i < 32; i += 2) {
    const float4* xr0 = (const float4*)(xbase + (long)i * 1024);
    const float4* xr1 = (const float4*)(xbase + (long)(i + 1) * 1024);
    float a0 = 0.f, a1 = 0.f, a2 = 0.f, a3 = 0.f;
    float b0 = 0.f, b1 = 0.f, b2 = 0.f, b3 = 0.f;
#pragma unroll
    for (int j = 0; j < 32; j += 4) {
      float4 xa0 = xr0[j],     xa1 = xr0[j + 1], xa2 = xr0[j + 2], xa3 = xr0[j + 3];
      float4 xb0 = xr1[j],     xb1 = xr1[j + 1], xb2 = xr1[j + 2], xb3 = xr1[j + 3];
      a0 += wreg[4*j+0]*xa0.x  + wreg[4*j+1]*xa0.y  + wreg[4*j+2]*xa0.z  + wreg[4*j+3]*xa0.w;
      a1 += wreg[4*j+4]*xa1.x  + wreg[4*j+5]*xa1.y  + wreg[4*j+6]*xa1.z  + wreg[4*j+7]*xa1.w;
      a2 += wreg[4*j+8]*xa2.x  + wreg[4*j+9]*xa2.y  + wreg[4*j+10]*xa2.z + wreg[4*j+11]*xa2.w;
      a3 += wreg[4*j+12]*xa3.x + wreg[4*j+13]*xa3.y + wreg[4*j+14]*xa3.z + wreg[4*j+15]*xa3.w;
      b0 += wreg[4*j+0]*xb0.x  + wreg[4*j+1]*xb0.y  + wreg[4*j+2]*xb0.z  + wreg[4*j+3]*xb0.w;
      b1 += wreg[4*j+4]*xb1.x  + wreg[4*j+5]*xb1.y  + wreg[4*j+6]*xb1.z  + wreg[4*j+7]*xb1.w;
      b2 += wreg[4*j+8]*xb2.x  + wreg[4*j+9]*xb2.y  + wreg[4*j+10]*xb2.z + wreg[4*j+11]*xb2.w;
      b3 += wreg[4*j+12]*xb3.x + wreg[4*j+13]*xb3.y + wreg[4*j+14]*xb3.z + wreg[4*j+15]*xb3.w;
    }
    float2 s0 = rowstat[r0 + i];
    float2 s1 = rowstat[r0 + i + 1];
    po[(long)i * 64]       = s0.y * ((a0 + a1) + (a2 + a3)) - s0.x * s0.y * swsum;
    po[(long)(i + 1) * 64] = s1.y * ((b0 + b1) + (b2 + b3)) - s1.x * s1.y * swsum;
  }
}

// pre[t,m] = softplus(sum_kc part[kc][t][m] + pb[m])
__global__ __launch_bounds__(256) void pre_fin_k(const float* __restrict__ part,
                                                 const float* __restrict__ pb,
                                                 float* __restrict__ pre) {
  long i = (long)blockIdx.x * 256 + threadIdx.x;   // over T_*64
  int m = (int)(i & 63);
  float s = 0.f;
#pragma unroll
  for (int kc = 0; kc < 8; ++kc)
    s += part[(long)kc * T_ * 64 + i];
  float v = s + pb[m];
  float sp = fmaxf(v, 0.f) + log1pf(expf(-fabsf(v)));
  pre[i] = sp;
}

// ---------------- chunked complex reset-scan (f64 internal) ----------------
__global__ __launch_bounds__(256) void scan_p1(const float* __restrict__ pre, const int* __restrict__ start,
                                               const float* __restrict__ a, const float* __restrict__ bfr,
                                               double2* __restrict__ chA, double2* __restrict__ chB) {
  int ch = blockIdx.y * 256 + threadIdx.x;
  int m = ch >> 4, c = ch & 15;
  double dec = exp(-fabs((double)a[m]));
  double th = (double)bfr[c];
  double gre = dec * cos(th), gim = dec * sin(th);
  int j = blockIdx.x;
  int t0 = j * CHUNK;
  double pr = 1.0, pi = 0.0, sr = 0.0, si = 0.0;
  for (int t = t0; t < t0 + CHUNK; ++t) {
    double b = (double)pre[(long)t * 64 + m];
    if (start[t]) {
      pr = 0.0; pi = 0.0; sr = b; si = 0.0;
    } else {
      double nsr = gre * sr - gim * si + b;
      si = gre * si + gim * sr; sr = nsr;
      double npr = gre * pr - gim * pi;
      pi = gre * pi + gim * pr; pr = npr;
    }
  }
  chA[j * MC + ch] = make_double2(pr, pi);
  chB[j * MC + ch] = make_double2(sr, si);
}

// composes chunks: per-chunk carry, zeroes red, writes the final-state tail.
__global__ __launch_bounds__(256) void scan_p2(const double2* __restrict__ chA, const double2* __restrict__ chB,
                                               const float* __restrict__ state0,
                                               double2* __restrict__ carry, double* __restrict__ red,
                                               float* __restrict__ out_tail, int fmt) {
  if (blockIdx.x == 0 && threadIdx.x < 4) red[threadIdx.x] = 0.0;
  int ch = blockIdx.x * 256 + threadIdx.x;
  double cr = (double)state0[ch], ci = 0.0;
  for (int j = 0; j < NCH; ++j) {
    carry[j * MC + ch] = make_double2(cr, ci);
    double2 A = chA[j * MC + ch];
    double2 B = chB[j * MC + ch];
    double ncr = A.x * cr - A.y * ci + B.x;
    ci = A.x * ci + A.y * cr + B.y;
    cr = ncr;
  }
  if (fmt == 1024) {
    out_tail[ch] = (float)cr;
  } else {
    out_tail[2 * ch]     = (float)cr;
    out_tail[2 * ch + 1] = (float)ci;
  }
}

// reduction-only replay
__global__ __launch_bounds__(256) void scan_p3(const float* __restrict__ pre, const int* __restrict__ start,
                                               const float* __restrict__ a, const float* __restrict__ bfr,
                                               const double2* __restrict__ carry,
                                               double* __restrict__ red) {
  __shared__ double sbuf[12];
  int ch = blockIdx.y * 256 + threadIdx.x;
  int m = ch >> 4, c = ch & 15;
  double dec = exp(-fabs((double)a[m]));
  double th = (double)bfr[c];
  double gre = dec * cos(th), gim = dec * sin(th);
  int j = blockIdx.x;
  int t0 = j * CHUNK;
  double2 cin = carry[j * MC + ch];
  double sr = cin.x, si = cin.y;
  double aR = 0.0, aI = 0.0, aS = 0.0;
  for (int t = t0; t < t0 + CHUNK; ++t) {
    double b = (double)pre[(long)t * 64 + m];
    if (start[t]) { sr = b; si = 0.0; }
    else {
      double nsr = gre * sr - gim * si + b;
      si = gre * si + gim * sr; sr = nsr;
    }
    aR += sr; aI += si; aS += sr * sr + si * si;
  }
#pragma unroll
  for (int off = 32; off > 0; off >>= 1) {
    aR += __shfl_down(aR, off); aI += __shfl_down(aI, off); aS += __shfl_down(aS, off);
  }
  if ((threadIdx.x & 63) == 0) {
    int w = threadIdx.x >> 6;
    sbuf[w * 3] = aR; sbuf[w * 3 + 1] = aI; sbuf[w * 3 + 2] = aS;
  }
  __syncthreads();
  if (threadIdx.x == 0) {
    atomicAdd(&red[0], sbuf[0] + sbuf[3] + sbuf[6] + sbuf[9]);
    atomicAdd(&red[1], sbuf[1] + sbuf[4] + sbuf[7] + sbuf[10]);
    atomicAdd(&red[2], sbuf[2] + sbuf[5] + sbuf[8] + sbuf[11]);
  }
}

__global__ void finalize_red(const double* __restrict__ red, float* __restrict__ redf) {
  const double n = (double)T_ * (double)MC;
  double mre = red[0] / n, mim = red[1] / n;
  double var = red[2] / n - mre * mre - mim * mim;
  double sd = sqrt(var > 0.0 ? var : 0.0);
  redf[0] = (float)mre;
  redf[1] = (float)mim;
  redf[2] = (float)(1.0 / (1e-6 + sd));
}

// replay scan AFTER finalize_red; write normalized bf16 z directly.
__global__ __launch_bounds__(256) void zscan_k(const float* __restrict__ pre, const int* __restrict__ start,
                                               const float* __restrict__ a, const float* __restrict__ bfr,
                                               const double2* __restrict__ carry, const float* __restrict__ redf,
                                               unsigned short* __restrict__ z) {
  int ch = blockIdx.y * 256 + threadIdx.x;
  int m = ch >> 4, c = ch & 15;
  double dec = exp(-fabs((double)a[m]));
  double th = (double)bfr[c];
  double gre = dec * cos(th), gim = dec * sin(th);
  int j = blockIdx.x;
  int t0 = j * CHUNK;
  double2 cin = carry[j * MC + ch];
  double sr = cin.x, si = cin.y;
  const float mre = redf[0], mim = redf[1], inv = redf[2];
  for (int t = t0; t < t0 + CHUNK; ++t) {
    double b = (double)pre[(long)t * 64 + m];
    if (start[t]) { sr = b; si = 0.0; }
    else {
      double nsr = gre * sr - gim * si + b;
      si = gre * si + gim * sr; sr = nsr;
    }
    z[(long)t * 2048 + ch]        = f2bf(((float)sr - mre) * inv);
    z[(long)t * 2048 + 1024 + ch] = f2bf(((float)si - mim) * inv);
  }
}

// ---------------- bf16 MFMA GEMM: double-buffered 2-phase (T3 minimum), XOR-swizzled LDS ----------------
// C[t,o] = sum_k A[t,k]*B[o,k] + bias[o] [+ add].  EP: 0 = f32, 2 = mish bf16, 3 = f32 + add[]
template<int EP>
__global__ __launch_bounds__(256) void gemm_bt(const unsigned short* __restrict__ A,
                                               const unsigned short* __restrict__ B,
                                               const float* __restrict__ bias,
                                               const float* __restrict__ add,
                                               void* __restrict__ Cout,
                                               int M_, int N_, int K_) {
  __shared__ __align__(16) unsigned short lA[2][128 * 32];
  __shared__ __align__(16) unsigned short lB[2][128 * 32];
  const int tid = threadIdx.x;
  const int lane = tid & 63;
  const int wv = tid >> 6;
  const int wr = wv >> 1, wc = wv & 1;
  const long brow = (long)blockIdx.x * 128;
  const long bcol = (long)blockIdx.y * 128;

  f32x4 acc[4][4];
#pragma unroll
  for (int i = 0; i < 4; i++)
#pragma unroll
    for (int j = 0; j < 4; j++)
      acc[i][j] = f32x4{0.f, 0.f, 0.f, 0.f};

  const int c0 = tid, c1 = tid + 256;
  const long ar0 = brow + (c0 >> 2), ar1 = brow + (c1 >> 2);
  const long br0 = bcol + (c0 >> 2), br1 = bcol + (c1 >> 2);
  const int ko0 = (((c0 & 3) ^ ((c0 >> 3) & 3)) * 8);
  const int ko1 = (((c1 & 3) ^ ((c1 >> 3) & 3)) * 8);
  const int r15 = lane & 15;
  const int swzq = (((lane >> 4) ^ ((r15 >> 1) & 3)) * 8);

  // prologue: stage tile 0 into buffer 0
  gload_lds16(A + ar0 * K_ + ko0, &lA[0][c0 * 8]);
  gload_lds16(A + ar1 * K_ + ko1, &lA[0][c1 * 8]);
  gload_lds16(B + br0 * K_ + ko0, &lB[0][c0 * 8]);
  gload_lds16(B + br1 * K_ + ko1, &lB[0][c1 * 8]);

  int cur = 0;
  for (int kt = 0; kt < K_; kt += 32) {
    const int nxt = cur ^ 1;
    if (kt + 32 < K_) {
      // issue next-tile loads BEFORE computing current tile (2-phase overlap)
      gload_lds16(A + ar0 * K_ + (kt + 32) + ko0, &lA[nxt][c0 * 8]);
      gload_lds16(A + ar1 * K_ + (kt + 32) + ko1, &lA[nxt][c1 * 8]);
      gload_lds16(B + br0 * K_ + (kt + 32) + ko0, &lB[nxt][c0 * 8]);
      gload_lds16(B + br1 * K_ + (kt + 32) + ko1, &lB[nxt][c1 * 8]);
      asm volatile("s_waitcnt vmcnt(4)" ::: "memory");   // wait CURRENT tile only (counted, not 0)
    } else {
      asm volatile("s_waitcnt vmcnt(0)" ::: "memory");
    }
    __builtin_amdgcn_sched_barrier(0);
    __builtin_amdgcn_s_barrier();            // raw barrier: no vmcnt(0) auto-drain
    __builtin_amdgcn_sched_barrier(0);

    bf16x8 af[4], bv[4];
#pragma unroll
    for (int mi = 0; mi < 4; mi++)
      af[mi] = *(const bf16x8*)&lA[cur][(wr * 64 + mi * 16 + r15) * 32 + swzq];
#pragma unroll
    for (int nj = 0; nj < 4; nj++)
      bv[nj] = *(const bf16x8*)&lB[cur][(wc * 64 + nj * 16 + r15) * 32 + swzq];
#pragma unroll
    for (int mi = 0; mi < 4; mi++)
#pragma unroll
      for (int nj = 0; nj < 4; nj++)
        acc[mi][nj] = __builtin_amdgcn_mfma_f32_16x16x32_bf16(af[mi], bv[nj], acc[mi][nj], 0, 0, 0);

    __builtin_amdgcn_sched_barrier(0);
    __builtin_amdgcn_s_barrier();            // all waves done reading buf[cur] before it is restaged
    cur = nxt;
  }

  const int rq = (lane >> 4) * 4;
#pragma unroll
  for (int nj = 0; nj < 4; nj++) {
    const long col = bcol + wc * 64 + nj * 16 + r15;
    const float bs = bias[col];
#pragma unroll
    for (int mi = 0; mi < 4; mi++) {
#pragma unroll
      for (int r = 0; r < 4; r++) {
        const long row = brow + wr * 64 + mi * 16 + rq + r;
        float v = acc[mi][nj][r] + bs;
        if (EP == 0) {
          ((float*)Cout)[row * N_ + col] = v;
        } else if (EP == 3) {
          ((float*)Cout)[row * N_ + col] = v + add[row * N_ + col];
        } else {
          ((unsigned short*)Cout)[row * N_ + col] = f2bf(mish_f(v));
        }
      }
    }
  }
}

// ---------------- host-side orchestration ----------------
extern "C" void kernel_launch(void* const* d_in, const int* in_sizes, int n_in,
                              void* d_out, int out_size, void* d_ws, size_t ws_size,
                              hipStream_t stream) {
  (void)in_sizes; (void)n_in; (void)ws_size;
  const float* x      = (const float*)d_in[0];
  const float* state0 = (const float*)d_in[1];
  const int*   start  = (const int*)d_in[2];
  const float* a      = (const float*)d_in[4];
  const float* bfr    = (const float*)d_in[5];
  const float* pre_w  = (const float*)d_in[6];
  const float* pre_b  = (const float*)d_in[7];
  const float* skip_w = (const float*)d_in[8];
  const float* skip_b = (const float*)d_in[9];
  const float* w1     = (const float*)d_in[10];
  const float* b1     = (const float*)d_in[11];
  const float* w2     = (const float*)d_in[12];
  const float* b2     = (const float*)d_in[13];
  const float* w3     = (const float*)d_in[14];
  const float* b3     = (const float*)d_in[15];

  char* ws = (char*)d_ws;
  const size_t MB = 1u << 20;
  float*          skipf = (float*)(ws + 0);          // skip GEMM out (f32)
  float*          part  = (float*)(ws + 32 * MB);    // 16MB [8][T][64]; dead after pre_fin_k
  float*          h3    = (float*)(ws + 32 * MB);    // mix3 out (+skip), after part dead
  unsigned short* z     = (unsigned short*)(ws + 64 * MB);
  unsigned short* xb    = (unsigned short*)(ws + 96 * MB);   // reused as h2 after skip GEMM
  unsigned short* h2    = (unsigned short*)(ws + 96 * MB);
  unsigned short* h1    = (unsigned short*)(ws + 112 * MB);
  unsigned short* wb1   = (unsigned short*)(ws + 128 * MB);
  unsigned short* wb2   = (unsigned short*)(ws + 132 * MB);
  unsigned short* wb3   = (unsigned short*)(ws + 134 * MB);
  unsigned short* skwb  = (unsigned short*)(ws + 136 * MB);
  float*          pre   = (float*)(ws + 138 * MB);
  double2*        chA   = (double2*)(ws + 140 * MB);
  double2*        chB   = (double2*)(ws + 142 * MB);
  double2*        carry = (double2*)(ws + 144 * MB);
  double*         red   = (double*)(ws + 146 * MB);
  float*          redf  = (float*)(ws + 146 * MB + 64);
  float2*         rowst = (float2*)(ws + 147 * MB);  // 64KB [T] (mean, rstd)

  // 1) merged weight casts
  cast4_k<<<5120, 256, 0, stream>>>(w1, w2, w3, skip_w, wb1, wb2, wb3, skwb);

  // 2) LN stats + bf16(x); exact-f32 pre-projection (register weights, algebraic LN)
  ln_cast_k<<<8192, 256, 0, stream>>>(x, rowst, xb);
  pre_part_k<<<dim3(64, 8), 256, 0, stream>>>(x, rowst, pre_w, part);
  pre_fin_k<<<2048, 256, 0, stream>>>(part, pre_b, pre);

  // 3) chunked scan; p2 composes carries and writes the final-state tail directly
  int tail_elems = out_size - T_ * NOUT;          // 1024 (real only) or 2048 (interleaved)
  float* out_tail = (float*)d_out + (long)T_ * NOUT;
  scan_p1<<<dim3(NCH, 4), 256, 0, stream>>>(pre, start, a, bfr, chA, chB);
  scan_p2<<<4, 256, 0, stream>>>(chA, chB, state0, carry, red, out_tail, tail_elems);
  scan_p3<<<dim3(NCH, 4), 256, 0, stream>>>(pre, start, a, bfr, carry, red);
  finalize_red<<<1, 1, 0, stream>>>(red, redf);

  // 4) replay scan -> normalized bf16 z
  zscan_k<<<dim3(NCH, 4), 256, 0, stream>>>(pre, start, a, bfr, carry, redf, z);

  // 5) skip GEMM, then the 3-layer mish MLP (mix3 fuses the skip add)
  gemm_bt<0><<<dim3(64, 8), 256, 0, stream>>>(xb, skwb, skip_b, nullptr, skipf, T_, 1024, 1024);
  gemm_bt<2><<<dim3(64, 8), 256, 0, stream>>>(z,  wb1, b1, nullptr, h1, T_, 1024, 2048);
  gemm_bt<2><<<dim3(64, 8), 256, 0, stream>>>(h1, wb2, b2, nullptr, h2, T_, 1024, 1024);
  gemm_bt<3><<<dim3(64, 8), 256, 0, stream>>>(h2, wb3, b3, skipf, h3, T_, 1024, 1024);

  // 6) out = LN(h3)  (h3 already includes skip)
  ln_out1_k<<<8192, 256, 0, stream>>>(h3, (float*)d_out);
}